// Round 1
// baseline (952.993 us; speedup 1.0000x reference)
//
#include <hip/hip_runtime.h>

// Problem constants (from reference): N=100000 nodes, E=1600000 edges,
// F=128 features everywhere, G=1000 graphs.
#define FDIM 128

// ---------------------------------------------------------------------------
// CSR build: count -> exclusive scan (2-level) -> fill
// ---------------------------------------------------------------------------

__global__ void count_dst(const int* __restrict__ dst, int* __restrict__ cnt, int E) {
    for (int e = blockIdx.x * blockDim.x + threadIdx.x; e < E;
         e += gridDim.x * blockDim.x)
        atomicAdd(&cnt[dst[e]], 1);
}

__global__ void compute_dinv(const int* __restrict__ cnt, float* __restrict__ dinv, int n) {
    int i = blockIdx.x * blockDim.x + threadIdx.x;
    if (i < n) dinv[i] = rsqrtf((float)cnt[i] + 1.0f);  // +1 for self-loop
}

// per-block (1024 elems) exclusive scan; block sums to bsum
__global__ void scan1(const int* __restrict__ cnt, int* __restrict__ rp,
                      int* __restrict__ bsum, int n) {
    __shared__ int s[2][1024];
    int t = threadIdx.x;
    int i = blockIdx.x * 1024 + t;
    int v = (i < n) ? cnt[i] : 0;
    s[0][t] = v;
    __syncthreads();
    int cur = 0;
    for (int off = 1; off < 1024; off <<= 1) {
        int x = s[cur][t];
        if (t >= off) x += s[cur][t - off];
        s[cur ^ 1][t] = x;
        cur ^= 1;
        __syncthreads();
    }
    int incl = s[cur][t];
    if (i < n) rp[i] = incl - v;           // exclusive within block
    if (t == 1023) bsum[blockIdx.x] = incl; // block total
}

// single-block exclusive scan of block sums (nb <= 128)
__global__ void scan2(int* bsum, int nb) {
    __shared__ int s[2][128];
    int t = threadIdx.x;
    int v = (t < nb) ? bsum[t] : 0;
    s[0][t] = v;
    __syncthreads();
    int cur = 0;
    for (int off = 1; off < 128; off <<= 1) {
        int x = s[cur][t];
        if (t >= off) x += s[cur][t - off];
        s[cur ^ 1][t] = x;
        cur ^= 1;
        __syncthreads();
    }
    if (t < nb) bsum[t] = s[cur][t] - v;   // exclusive
}

__global__ void scan3(int* __restrict__ rp, int* __restrict__ fill,
                      const int* __restrict__ bsum, int n, int E) {
    int i = blockIdx.x * blockDim.x + threadIdx.x;
    if (i < n) {
        int v = rp[i] + bsum[i >> 10];
        rp[i] = v;
        fill[i] = v;
    }
    if (i == 0) rp[n] = E;
}

__global__ void fill_csr(const int* __restrict__ src, const int* __restrict__ dst,
                         const float* __restrict__ dinv, int* __restrict__ fill,
                         int* __restrict__ src_e, float* __restrict__ norm_e, int E) {
    for (int e = blockIdx.x * blockDim.x + threadIdx.x; e < E;
         e += gridDim.x * blockDim.x) {
        int s = src[e], d = dst[e];
        int p = atomicAdd(&fill[d], 1);
        src_e[p] = s;
        norm_e[p] = dinv[s] * dinv[d];
    }
}

__global__ void graph_counts(const int* __restrict__ batch, int* __restrict__ gcnt, int n) {
    int i = blockIdx.x * blockDim.x + threadIdx.x;
    if (i < n) atomicAdd(&gcnt[batch[i]], 1);
}

// ---------------------------------------------------------------------------
// Dense transform: Y[n][128] = X[n][128] @ W[128][128].  W staged in LDS.
// block = 256 threads = 2 rows x 128 cols, grid-stride over rows.
// ---------------------------------------------------------------------------
__global__ __launch_bounds__(256) void gemm128(const float* __restrict__ X,
                                               const float* __restrict__ W,
                                               float* __restrict__ Y, int n) {
    __shared__ float Ws[FDIM * FDIM];     // 64 KiB
    __shared__ float xs[2][FDIM];
    for (int i = threadIdx.x; i < FDIM * FDIM; i += 256) Ws[i] = W[i];
    int j  = threadIdx.x & 127;
    int rh = threadIdx.x >> 7;            // 0..1
    for (int r0 = blockIdx.x * 2; r0 < n; r0 += gridDim.x * 2) {
        int r = r0 + rh;
        __syncthreads();                  // protects xs reuse + first-iter W load
        if (r < n) xs[rh][j] = X[r * FDIM + j];
        __syncthreads();
        if (r < n) {
            float acc = 0.f;
#pragma unroll
            for (int k = 0; k < FDIM; ++k)
                acc = fmaf(xs[rh][k], Ws[k * FDIM + j], acc);
            Y[r * FDIM + j] = acc;
        }
    }
}

// ---------------------------------------------------------------------------
// Aggregation: out[n] = sum_{e in CSR[n]} norm_e * hw[src_e]  + dinv[n]^2*hw[n] + b
// One wave (64 lanes) per node, float2 per lane (covers 128 feats).
// ---------------------------------------------------------------------------
__global__ __launch_bounds__(256) void aggregate_relu(
        const float* __restrict__ hw, const int* __restrict__ rp,
        const int* __restrict__ src_e, const float* __restrict__ norm_e,
        const float* __restrict__ dinv, const float* __restrict__ bias,
        float* __restrict__ out, int n) {
    int lane = threadIdx.x & 63;
    int node = blockIdx.x * 4 + (threadIdx.x >> 6);
    if (node >= n) return;
    const float2* hw2 = (const float2*)hw;
    int e0 = rp[node], e1 = rp[node + 1];
    float ax = 0.f, ay = 0.f;
    int e = e0;
    for (; e + 4 <= e1; e += 4) {
        int   s0 = src_e[e], s1 = src_e[e + 1], s2 = src_e[e + 2], s3 = src_e[e + 3];
        float w0 = norm_e[e], w1 = norm_e[e + 1], w2 = norm_e[e + 2], w3 = norm_e[e + 3];
        float2 v0 = hw2[s0 * 64 + lane];
        float2 v1 = hw2[s1 * 64 + lane];
        float2 v2 = hw2[s2 * 64 + lane];
        float2 v3 = hw2[s3 * 64 + lane];
        ax += w0 * v0.x + w1 * v1.x + w2 * v2.x + w3 * v3.x;
        ay += w0 * v0.y + w1 * v1.y + w2 * v2.y + w3 * v3.y;
    }
    for (; e < e1; ++e) {
        float w = norm_e[e];
        float2 v = hw2[src_e[e] * 64 + lane];
        ax += w * v.x;
        ay += w * v.y;
    }
    float dv = dinv[node];
    float2 self = hw2[node * 64 + lane];
    float2 b = ((const float2*)bias)[lane];
    ax += dv * dv * self.x + b.x;
    ay += dv * dv * self.y + b.y;
    float2 r;
    r.x = fmaxf(ax, 0.f);
    r.y = fmaxf(ay, 0.f);
    ((float2*)out)[node * 64 + lane] = r;
}

__global__ __launch_bounds__(256) void aggregate_pool(
        const float* __restrict__ hw, const int* __restrict__ rp,
        const int* __restrict__ src_e, const float* __restrict__ norm_e,
        const float* __restrict__ dinv, const float* __restrict__ bias,
        const int* __restrict__ batch, float* __restrict__ pool, int n) {
    int lane = threadIdx.x & 63;
    int node = blockIdx.x * 4 + (threadIdx.x >> 6);
    if (node >= n) return;
    const float2* hw2 = (const float2*)hw;
    int e0 = rp[node], e1 = rp[node + 1];
    float ax = 0.f, ay = 0.f;
    int e = e0;
    for (; e + 4 <= e1; e += 4) {
        int   s0 = src_e[e], s1 = src_e[e + 1], s2 = src_e[e + 2], s3 = src_e[e + 3];
        float w0 = norm_e[e], w1 = norm_e[e + 1], w2 = norm_e[e + 2], w3 = norm_e[e + 3];
        float2 v0 = hw2[s0 * 64 + lane];
        float2 v1 = hw2[s1 * 64 + lane];
        float2 v2 = hw2[s2 * 64 + lane];
        float2 v3 = hw2[s3 * 64 + lane];
        ax += w0 * v0.x + w1 * v1.x + w2 * v2.x + w3 * v3.x;
        ay += w0 * v0.y + w1 * v1.y + w2 * v2.y + w3 * v3.y;
    }
    for (; e < e1; ++e) {
        float w = norm_e[e];
        float2 v = hw2[src_e[e] * 64 + lane];
        ax += w * v.x;
        ay += w * v.y;
    }
    float dv = dinv[node];
    float2 self = hw2[node * 64 + lane];
    float2 b = ((const float2*)bias)[lane];
    ax += dv * dv * self.x + b.x;   // layer 2: no relu
    ay += dv * dv * self.y + b.y;
    int g = batch[node];
    atomicAdd(&pool[g * FDIM + lane * 2],     ax);
    atomicAdd(&pool[g * FDIM + lane * 2 + 1], ay);
}

__global__ void pool_div(float* __restrict__ out, const int* __restrict__ gcnt, int total) {
    int i = blockIdx.x * blockDim.x + threadIdx.x;
    if (i < total) {
        int g = i >> 7;
        out[i] /= fmaxf((float)gcnt[g], 1.0f);
    }
}

// ---------------------------------------------------------------------------

extern "C" void kernel_launch(void* const* d_in, const int* in_sizes, int n_in,
                              void* d_out, int out_size, void* d_ws, size_t ws_size,
                              hipStream_t stream) {
    const float* x     = (const float*)d_in[0];
    const int*   ei    = (const int*)d_in[1];
    const int*   batch = (const int*)d_in[2];
    const float* W1    = (const float*)d_in[3];
    const float* b1    = (const float*)d_in[4];
    const float* W2    = (const float*)d_in[5];
    const float* b2    = (const float*)d_in[6];
    float* out = (float*)d_out;

    const int N = in_sizes[0] / FDIM;      // 100000
    const int E = in_sizes[1] / 2;         // 1600000
    const int G = out_size / FDIM;         // 1000
    const int* src = ei;
    const int* dst = ei + E;

    // workspace layout
    char* p = (char*)d_ws;
    auto alloc = [&](size_t bytes) {
        void* r = (void*)p;
        p += (bytes + 255) & ~(size_t)255;
        return r;
    };
    float* dinv   = (float*)alloc((size_t)N * 4);
    int*   cnt    = (int*)  alloc((size_t)N * 4);
    int*   rp     = (int*)  alloc((size_t)(N + 1) * 4);
    int*   fill   = (int*)  alloc((size_t)N * 4);
    int*   bsum   = (int*)  alloc(128 * 4);
    int*   gcnt   = (int*)  alloc((size_t)G * 4);
    int*   src_e  = (int*)  alloc((size_t)E * 4);
    float* norm_e = (float*)alloc((size_t)E * 4);
    float* hw     = (float*)alloc((size_t)N * FDIM * 4);
    float* h1     = (float*)alloc((size_t)N * FDIM * 4);

    hipMemsetAsync(cnt, 0, (size_t)N * 4, stream);
    hipMemsetAsync(gcnt, 0, (size_t)G * 4, stream);
    hipMemsetAsync(out, 0, (size_t)G * FDIM * 4, stream);

    const int NB = (N + 1023) / 1024;      // 98 scan blocks

    count_dst<<<2048, 256, 0, stream>>>(dst, cnt, E);
    compute_dinv<<<(N + 255) / 256, 256, 0, stream>>>(cnt, dinv, N);
    scan1<<<NB, 1024, 0, stream>>>(cnt, rp, bsum, N);
    scan2<<<1, 128, 0, stream>>>(bsum, NB);
    scan3<<<(N + 255) / 256, 256, 0, stream>>>(rp, fill, bsum, N, E);
    fill_csr<<<2048, 256, 0, stream>>>(src, dst, dinv, fill, src_e, norm_e, E);
    graph_counts<<<(N + 255) / 256, 256, 0, stream>>>(batch, gcnt, N);

    // layer 1
    gemm128<<<2048, 256, 0, stream>>>(x, W1, hw, N);
    aggregate_relu<<<(N + 3) / 4, 256, 0, stream>>>(hw, rp, src_e, norm_e, dinv, b1, h1, N);
    // layer 2 (+ fused pool)
    gemm128<<<2048, 256, 0, stream>>>(h1, W2, hw, N);
    aggregate_pool<<<(N + 3) / 4, 256, 0, stream>>>(hw, rp, src_e, norm_e, dinv, b2, batch, out, N);
    pool_div<<<(G * FDIM + 255) / 256, 256, 0, stream>>>(out, gcnt, G * FDIM);
}

// Round 2
// 654.490 us; speedup vs baseline: 1.4561x; 1.4561x over previous
//
#include <hip/hip_runtime.h>

// N=100000 nodes, E=1600000 edges, F=128, G=1000 graphs.
#define FDIM 128
#define BROWS 64
#define KCH 16
#define NCH (FDIM / KCH)   // 8 chunks

// ---------------------------------------------------------------------------
// CSR build: count -> exclusive scan (2-level) -> fill
// ---------------------------------------------------------------------------

__global__ void count_dst(const int* __restrict__ dst, int* __restrict__ cnt, int E) {
    for (int e = blockIdx.x * blockDim.x + threadIdx.x; e < E;
         e += gridDim.x * blockDim.x)
        atomicAdd(&cnt[dst[e]], 1);
}

__global__ void compute_dinv(const int* __restrict__ cnt, float* __restrict__ dinv, int n) {
    int i = blockIdx.x * blockDim.x + threadIdx.x;
    if (i < n) dinv[i] = rsqrtf((float)cnt[i] + 1.0f);  // +1 for self-loop
}

__global__ void scan1(const int* __restrict__ cnt, int* __restrict__ rp,
                      int* __restrict__ bsum, int n) {
    __shared__ int s[2][1024];
    int t = threadIdx.x;
    int i = blockIdx.x * 1024 + t;
    int v = (i < n) ? cnt[i] : 0;
    s[0][t] = v;
    __syncthreads();
    int cur = 0;
    for (int off = 1; off < 1024; off <<= 1) {
        int x = s[cur][t];
        if (t >= off) x += s[cur][t - off];
        s[cur ^ 1][t] = x;
        cur ^= 1;
        __syncthreads();
    }
    int incl = s[cur][t];
    if (i < n) rp[i] = incl - v;
    if (t == 1023) bsum[blockIdx.x] = incl;
}

__global__ void scan2(int* bsum, int nb) {
    __shared__ int s[2][128];
    int t = threadIdx.x;
    int v = (t < nb) ? bsum[t] : 0;
    s[0][t] = v;
    __syncthreads();
    int cur = 0;
    for (int off = 1; off < 128; off <<= 1) {
        int x = s[cur][t];
        if (t >= off) x += s[cur][t - off];
        s[cur ^ 1][t] = x;
        cur ^= 1;
        __syncthreads();
    }
    if (t < nb) bsum[t] = s[cur][t] - v;
}

__global__ void scan3(int* __restrict__ rp, int* __restrict__ fill,
                      const int* __restrict__ bsum, int n, int E) {
    int i = blockIdx.x * blockDim.x + threadIdx.x;
    if (i < n) {
        int v = rp[i] + bsum[i >> 10];
        rp[i] = v;
        fill[i] = v;
    }
    if (i == 0) rp[n] = E;
}

__global__ void fill_csr(const int* __restrict__ src, const int* __restrict__ dst,
                         const float* __restrict__ dinv, int* __restrict__ fill,
                         int* __restrict__ src_e, float* __restrict__ norm_e, int E) {
    for (int e = blockIdx.x * blockDim.x + threadIdx.x; e < E;
         e += gridDim.x * blockDim.x) {
        int s = src[e], d = dst[e];
        int p = atomicAdd(&fill[d], 1);
        src_e[p] = s;
        norm_e[p] = dinv[s] * dinv[d];
    }
}

__global__ void graph_counts(const int* __restrict__ batch, int* __restrict__ gcnt, int n) {
    int i = blockIdx.x * blockDim.x + threadIdx.x;
    if (i < n) atomicAdd(&gcnt[batch[i]], 1);
}

// ---------------------------------------------------------------------------
// Register-blocked dense transform: Y[n][128] = X[n][128] @ W[128][128].
// Block: 256 thr, 64 rows x 128 cols. Thread: 4 rows x 8 cols (cols 4c, 64+4c).
// W full in LDS (64 KiB); X double-buffered in 16-k chunks (10 KiB).
// ---------------------------------------------------------------------------
__global__ __launch_bounds__(256) void gemm128(const float* __restrict__ X,
                                               const float* __restrict__ W,
                                               float* __restrict__ Y, int n) {
    __shared__ float Ws[FDIM * FDIM];          // 64 KiB
    __shared__ float xs[2][BROWS][KCH + 4];    // 2*64*20*4 = 10 KiB (pad 4 keeps f4 align)

    const int tid  = threadIdx.x;
    const int c    = tid & 15;                 // col group: cols 4c.. and 64+4c..
    const int r    = tid >> 4;                 // 0..15; rows r,r+16,r+32,r+48
    const int srow = tid >> 2;                 // staging row 0..63
    const int skk  = (tid & 3) << 2;           // staging k offset 0/4/8/12
    const int r0   = blockIdx.x * BROWS;

    for (int i = tid; i < FDIM * FDIM; i += 256) Ws[i] = W[i];

    const int grow  = r0 + srow;
    const bool rowok = grow < n;
    const float* xrow = X + (size_t)grow * FDIM + skk;

    float4 v = rowok ? *(const float4*)xrow : float4{0.f, 0.f, 0.f, 0.f};
    *(float4*)&xs[0][srow][skk] = v;
    __syncthreads();

    float accA[4][4], accB[4][4];
#pragma unroll
    for (int m = 0; m < 4; ++m)
#pragma unroll
        for (int i = 0; i < 4; ++i) { accA[m][i] = 0.f; accB[m][i] = 0.f; }

    for (int ch = 0; ch < NCH; ++ch) {
        const int b = ch & 1;
        float4 nv{0.f, 0.f, 0.f, 0.f};
        if (ch + 1 < NCH && rowok)
            nv = *(const float4*)(xrow + (ch + 1) * KCH);
        const int k0 = ch * KCH;
#pragma unroll
        for (int k4 = 0; k4 < KCH; k4 += 4) {
            float4 xv0 = *(const float4*)&xs[b][r][k4];
            float4 xv1 = *(const float4*)&xs[b][r + 16][k4];
            float4 xv2 = *(const float4*)&xs[b][r + 32][k4];
            float4 xv3 = *(const float4*)&xs[b][r + 48][k4];
#define GSTEP(kk, comp)                                                        \
            {                                                                  \
                const float* wp = &Ws[(k0 + k4 + kk) * FDIM + 4 * c];          \
                const float4 w0 = *(const float4*)wp;                          \
                const float4 w1 = *(const float4*)(wp + 64);                   \
                const float xr[4] = {xv0.comp, xv1.comp, xv2.comp, xv3.comp};  \
                _Pragma("unroll")                                              \
                for (int m = 0; m < 4; ++m) {                                  \
                    accA[m][0] = fmaf(xr[m], w0.x, accA[m][0]);                \
                    accA[m][1] = fmaf(xr[m], w0.y, accA[m][1]);                \
                    accA[m][2] = fmaf(xr[m], w0.z, accA[m][2]);                \
                    accA[m][3] = fmaf(xr[m], w0.w, accA[m][3]);                \
                    accB[m][0] = fmaf(xr[m], w1.x, accB[m][0]);                \
                    accB[m][1] = fmaf(xr[m], w1.y, accB[m][1]);                \
                    accB[m][2] = fmaf(xr[m], w1.z, accB[m][2]);                \
                    accB[m][3] = fmaf(xr[m], w1.w, accB[m][3]);                \
                }                                                              \
            }
            GSTEP(0, x) GSTEP(1, y) GSTEP(2, z) GSTEP(3, w)
#undef GSTEP
        }
        if (ch + 1 < NCH)
            *(float4*)&xs[b ^ 1][srow][skk] = nv;
        __syncthreads();
    }

#pragma unroll
    for (int m = 0; m < 4; ++m) {
        int row = r0 + r + 16 * m;
        if (row < n) {
            float4 oa{accA[m][0], accA[m][1], accA[m][2], accA[m][3]};
            float4 ob{accB[m][0], accB[m][1], accB[m][2], accB[m][3]};
            *(float4*)&Y[(size_t)row * FDIM + 4 * c]      = oa;
            *(float4*)&Y[(size_t)row * FDIM + 64 + 4 * c] = ob;
        }
    }
}

// ---------------------------------------------------------------------------
// Aggregation: half-wave (32 lanes x float4) per node, 8 nodes / 256-block.
// ---------------------------------------------------------------------------
__global__ __launch_bounds__(256) void aggregate_relu(
        const float* __restrict__ hw, const int* __restrict__ rp,
        const int* __restrict__ src_e, const float* __restrict__ norm_e,
        const float* __restrict__ dinv, const float* __restrict__ bias,
        float* __restrict__ out, int n) {
    const int lane = threadIdx.x & 31;
    const int node = blockIdx.x * 8 + (threadIdx.x >> 5);
    if (node >= n) return;
    const float4* hw4 = (const float4*)hw;
    int e0 = rp[node], e1 = rp[node + 1];
    float4 a{0.f, 0.f, 0.f, 0.f};
    int e = e0;
    for (; e + 4 <= e1; e += 4) {
        int   s0 = src_e[e], s1 = src_e[e + 1], s2 = src_e[e + 2], s3 = src_e[e + 3];
        float w0 = norm_e[e], w1 = norm_e[e + 1], w2 = norm_e[e + 2], w3 = norm_e[e + 3];
        float4 v0 = hw4[s0 * 32 + lane];
        float4 v1 = hw4[s1 * 32 + lane];
        float4 v2 = hw4[s2 * 32 + lane];
        float4 v3 = hw4[s3 * 32 + lane];
        a.x += w0 * v0.x + w1 * v1.x + w2 * v2.x + w3 * v3.x;
        a.y += w0 * v0.y + w1 * v1.y + w2 * v2.y + w3 * v3.y;
        a.z += w0 * v0.z + w1 * v1.z + w2 * v2.z + w3 * v3.z;
        a.w += w0 * v0.w + w1 * v1.w + w2 * v2.w + w3 * v3.w;
    }
    for (; e < e1; ++e) {
        float w = norm_e[e];
        float4 vv = hw4[src_e[e] * 32 + lane];
        a.x += w * vv.x; a.y += w * vv.y; a.z += w * vv.z; a.w += w * vv.w;
    }
    float dv = dinv[node];
    float sn = dv * dv;
    float4 self = hw4[node * 32 + lane];
    float4 b = ((const float4*)bias)[lane];
    a.x = fmaxf(fmaf(sn, self.x, a.x) + b.x, 0.f);
    a.y = fmaxf(fmaf(sn, self.y, a.y) + b.y, 0.f);
    a.z = fmaxf(fmaf(sn, self.z, a.z) + b.z, 0.f);
    a.w = fmaxf(fmaf(sn, self.w, a.w) + b.w, 0.f);
    ((float4*)out)[node * 32 + lane] = a;
}

// Layer-2 aggregation fused with mean-pool accumulate. batch is SORTED, so
// merge same-graph nodes in LDS: ~1 atomic-set per block instead of 8.
__global__ __launch_bounds__(256) void aggregate_pool(
        const float* __restrict__ hw, const int* __restrict__ rp,
        const int* __restrict__ src_e, const float* __restrict__ norm_e,
        const float* __restrict__ dinv, const float* __restrict__ bias,
        const int* __restrict__ batch, float* __restrict__ pool, int n) {
    __shared__ float4 part[8][32];
    __shared__ int gs[8];
    const int lane = threadIdx.x & 31;
    const int half = threadIdx.x >> 5;
    const int node = blockIdx.x * 8 + half;
    const bool valid = node < n;
    const float4* hw4 = (const float4*)hw;
    int e0 = 0, e1 = 0;
    if (valid) { e0 = rp[node]; e1 = rp[node + 1]; }
    float4 a{0.f, 0.f, 0.f, 0.f};
    int e = e0;
    for (; e + 4 <= e1; e += 4) {
        int   s0 = src_e[e], s1 = src_e[e + 1], s2 = src_e[e + 2], s3 = src_e[e + 3];
        float w0 = norm_e[e], w1 = norm_e[e + 1], w2 = norm_e[e + 2], w3 = norm_e[e + 3];
        float4 v0 = hw4[s0 * 32 + lane];
        float4 v1 = hw4[s1 * 32 + lane];
        float4 v2 = hw4[s2 * 32 + lane];
        float4 v3 = hw4[s3 * 32 + lane];
        a.x += w0 * v0.x + w1 * v1.x + w2 * v2.x + w3 * v3.x;
        a.y += w0 * v0.y + w1 * v1.y + w2 * v2.y + w3 * v3.y;
        a.z += w0 * v0.z + w1 * v1.z + w2 * v2.z + w3 * v3.z;
        a.w += w0 * v0.w + w1 * v1.w + w2 * v2.w + w3 * v3.w;
    }
    for (; e < e1; ++e) {
        float w = norm_e[e];
        float4 vv = hw4[src_e[e] * 32 + lane];
        a.x += w * vv.x; a.y += w * vv.y; a.z += w * vv.z; a.w += w * vv.w;
    }
    if (valid) {
        float dv = dinv[node];
        float sn = dv * dv;
        float4 self = hw4[node * 32 + lane];
        float4 b = ((const float4*)bias)[lane];
        a.x = fmaf(sn, self.x, a.x) + b.x;
        a.y = fmaf(sn, self.y, a.y) + b.y;
        a.z = fmaf(sn, self.z, a.z) + b.z;
        a.w = fmaf(sn, self.w, a.w) + b.w;
    }
    part[half][lane] = a;
    if (lane == 0) gs[half] = valid ? batch[node] : -1;
    __syncthreads();
    if (half == 0) {
        float4 acc = part[0][lane];
        int g0 = gs[0];
#pragma unroll
        for (int h = 1; h < 8; ++h) {
            if (gs[h] == g0) {
                float4 p = part[h][lane];
                acc.x += p.x; acc.y += p.y; acc.z += p.z; acc.w += p.w;
            } else {
                if (g0 >= 0) {
                    float* dst = &pool[g0 * FDIM + lane * 4];
                    atomicAdd(dst + 0, acc.x); atomicAdd(dst + 1, acc.y);
                    atomicAdd(dst + 2, acc.z); atomicAdd(dst + 3, acc.w);
                }
                g0 = gs[h];
                acc = part[h][lane];
            }
        }
        if (g0 >= 0) {
            float* dst = &pool[g0 * FDIM + lane * 4];
            atomicAdd(dst + 0, acc.x); atomicAdd(dst + 1, acc.y);
            atomicAdd(dst + 2, acc.z); atomicAdd(dst + 3, acc.w);
        }
    }
}

__global__ void pool_div(float* __restrict__ out, const int* __restrict__ gcnt, int total) {
    int i = blockIdx.x * blockDim.x + threadIdx.x;
    if (i < total) {
        int g = i >> 7;
        out[i] /= fmaxf((float)gcnt[g], 1.0f);
    }
}

// ---------------------------------------------------------------------------

extern "C" void kernel_launch(void* const* d_in, const int* in_sizes, int n_in,
                              void* d_out, int out_size, void* d_ws, size_t ws_size,
                              hipStream_t stream) {
    const float* x     = (const float*)d_in[0];
    const int*   ei    = (const int*)d_in[1];
    const int*   batch = (const int*)d_in[2];
    const float* W1    = (const float*)d_in[3];
    const float* b1    = (const float*)d_in[4];
    const float* W2    = (const float*)d_in[5];
    const float* b2    = (const float*)d_in[6];
    float* out = (float*)d_out;

    const int N = in_sizes[0] / FDIM;      // 100000
    const int E = in_sizes[1] / 2;         // 1600000
    const int G = out_size / FDIM;         // 1000
    const int* src = ei;
    const int* dst = ei + E;

    char* p = (char*)d_ws;
    auto alloc = [&](size_t bytes) {
        void* r = (void*)p;
        p += (bytes + 255) & ~(size_t)255;
        return r;
    };
    float* dinv   = (float*)alloc((size_t)N * 4);
    int*   cnt    = (int*)  alloc((size_t)N * 4);
    int*   rp     = (int*)  alloc((size_t)(N + 1) * 4);
    int*   fill   = (int*)  alloc((size_t)N * 4);
    int*   bsum   = (int*)  alloc(128 * 4);
    int*   gcnt   = (int*)  alloc((size_t)G * 4);
    int*   src_e  = (int*)  alloc((size_t)E * 4);
    float* norm_e = (float*)alloc((size_t)E * 4);
    float* hw     = (float*)alloc((size_t)N * FDIM * 4);
    float* h1     = (float*)alloc((size_t)N * FDIM * 4);

    hipMemsetAsync(cnt, 0, (size_t)N * 4, stream);
    hipMemsetAsync(gcnt, 0, (size_t)G * 4, stream);
    hipMemsetAsync(out, 0, (size_t)G * FDIM * 4, stream);

    const int NB = (N + 1023) / 1024;

    count_dst<<<2048, 256, 0, stream>>>(dst, cnt, E);
    compute_dinv<<<(N + 255) / 256, 256, 0, stream>>>(cnt, dinv, N);
    scan1<<<NB, 1024, 0, stream>>>(cnt, rp, bsum, N);
    scan2<<<1, 128, 0, stream>>>(bsum, NB);
    scan3<<<(N + 255) / 256, 256, 0, stream>>>(rp, fill, bsum, N, E);
    fill_csr<<<2048, 256, 0, stream>>>(src, dst, dinv, fill, src_e, norm_e, E);
    graph_counts<<<(N + 255) / 256, 256, 0, stream>>>(batch, gcnt, N);

    const int GB = (N + BROWS - 1) / BROWS;   // 1563
    // layer 1
    gemm128<<<GB, 256, 0, stream>>>(x, W1, hw, N);
    aggregate_relu<<<(N + 7) / 8, 256, 0, stream>>>(hw, rp, src_e, norm_e, dinv, b1, h1, N);
    // layer 2 (+ fused pool)
    gemm128<<<GB, 256, 0, stream>>>(h1, W2, hw, N);
    aggregate_pool<<<(N + 7) / 8, 256, 0, stream>>>(hw, rp, src_e, norm_e, dinv, b2, batch, out, N);
    pool_div<<<(G * FDIM + 255) / 256, 256, 0, stream>>>(out, gcnt, G * FDIM);
}

// Round 3
// 567.409 us; speedup vs baseline: 1.6796x; 1.1535x over previous
//
#include <hip/hip_runtime.h>
#include <hip/hip_fp16.h>

// N=100000 nodes, E=1600000 edges, F=128, G=1000 graphs.
#define FDIM 128
#define BROWS 64
#define KCH 16
#define NCH (FDIM / KCH)   // 8 chunks

// ---------------------------------------------------------------------------
// CSR build: count -> exclusive scan (2-level) -> fill
// ---------------------------------------------------------------------------

__global__ void count_dst(const int* __restrict__ dst, int* __restrict__ cnt, int E) {
    for (int e = blockIdx.x * blockDim.x + threadIdx.x; e < E;
         e += gridDim.x * blockDim.x)
        atomicAdd(&cnt[dst[e]], 1);
}

__global__ void compute_dinv(const int* __restrict__ cnt, float* __restrict__ dinv, int n) {
    int i = blockIdx.x * blockDim.x + threadIdx.x;
    if (i < n) dinv[i] = rsqrtf((float)cnt[i] + 1.0f);  // +1 for self-loop
}

__global__ void scan1(const int* __restrict__ cnt, int* __restrict__ rp,
                      int* __restrict__ bsum, int n) {
    __shared__ int s[2][1024];
    int t = threadIdx.x;
    int i = blockIdx.x * 1024 + t;
    int v = (i < n) ? cnt[i] : 0;
    s[0][t] = v;
    __syncthreads();
    int cur = 0;
    for (int off = 1; off < 1024; off <<= 1) {
        int x = s[cur][t];
        if (t >= off) x += s[cur][t - off];
        s[cur ^ 1][t] = x;
        cur ^= 1;
        __syncthreads();
    }
    int incl = s[cur][t];
    if (i < n) rp[i] = incl - v;
    if (t == 1023) bsum[blockIdx.x] = incl;
}

__global__ void scan2(int* bsum, int nb) {
    __shared__ int s[2][128];
    int t = threadIdx.x;
    int v = (t < nb) ? bsum[t] : 0;
    s[0][t] = v;
    __syncthreads();
    int cur = 0;
    for (int off = 1; off < 128; off <<= 1) {
        int x = s[cur][t];
        if (t >= off) x += s[cur][t - off];
        s[cur ^ 1][t] = x;
        cur ^= 1;
        __syncthreads();
    }
    if (t < nb) bsum[t] = s[cur][t] - v;
}

__global__ void scan3(int* __restrict__ rp, int* __restrict__ fill,
                      const int* __restrict__ bsum, int n, int E) {
    int i = blockIdx.x * blockDim.x + threadIdx.x;
    if (i < n) {
        int v = rp[i] + bsum[i >> 10];
        rp[i] = v;
        fill[i] = v;
    }
    if (i == 0) rp[n] = E;
}

// Pack (src, norm) into one int2 per edge slot.
__global__ void fill_csr(const int* __restrict__ src, const int* __restrict__ dst,
                         const float* __restrict__ dinv, int* __restrict__ fill,
                         int2* __restrict__ em, int E) {
    for (int e = blockIdx.x * blockDim.x + threadIdx.x; e < E;
         e += gridDim.x * blockDim.x) {
        int s = src[e], d = dst[e];
        int p = atomicAdd(&fill[d], 1);
        em[p] = make_int2(s, __float_as_int(dinv[s] * dinv[d]));
    }
}

__global__ void graph_counts(const int* __restrict__ batch, int* __restrict__ gcnt, int n) {
    int i = blockIdx.x * blockDim.x + threadIdx.x;
    if (i < n) atomicAdd(&gcnt[batch[i]], 1);
}

// ---------------------------------------------------------------------------
// Register-blocked dense transform: Y16[n][128] = X[n][128] @ W[128][128],
// output packed fp16. Block: 256 thr, 64 rows x 128 cols; thread: 4x8.
// ---------------------------------------------------------------------------
__global__ __launch_bounds__(256) void gemm128(const float* __restrict__ X,
                                               const float* __restrict__ W,
                                               __half* __restrict__ Y, int n) {
    __shared__ float Ws[FDIM * FDIM];          // 64 KiB
    __shared__ float xs[2][BROWS][KCH + 4];    // 10 KiB

    const int tid  = threadIdx.x;
    const int c    = tid & 15;
    const int r    = tid >> 4;
    const int srow = tid >> 2;
    const int skk  = (tid & 3) << 2;
    const int r0   = blockIdx.x * BROWS;

    for (int i = tid; i < FDIM * FDIM; i += 256) Ws[i] = W[i];

    const int grow  = r0 + srow;
    const bool rowok = grow < n;
    const float* xrow = X + (size_t)grow * FDIM + skk;

    float4 v = rowok ? *(const float4*)xrow : float4{0.f, 0.f, 0.f, 0.f};
    *(float4*)&xs[0][srow][skk] = v;
    __syncthreads();

    float accA[4][4], accB[4][4];
#pragma unroll
    for (int m = 0; m < 4; ++m)
#pragma unroll
        for (int i = 0; i < 4; ++i) { accA[m][i] = 0.f; accB[m][i] = 0.f; }

    for (int ch = 0; ch < NCH; ++ch) {
        const int b = ch & 1;
        float4 nv{0.f, 0.f, 0.f, 0.f};
        if (ch + 1 < NCH && rowok)
            nv = *(const float4*)(xrow + (ch + 1) * KCH);
        const int k0 = ch * KCH;
#pragma unroll
        for (int k4 = 0; k4 < KCH; k4 += 4) {
            float4 xv0 = *(const float4*)&xs[b][r][k4];
            float4 xv1 = *(const float4*)&xs[b][r + 16][k4];
            float4 xv2 = *(const float4*)&xs[b][r + 32][k4];
            float4 xv3 = *(const float4*)&xs[b][r + 48][k4];
#define GSTEP(kk, comp)                                                        \
            {                                                                  \
                const float* wp = &Ws[(k0 + k4 + kk) * FDIM + 4 * c];          \
                const float4 w0 = *(const float4*)wp;                          \
                const float4 w1 = *(const float4*)(wp + 64);                   \
                const float xr[4] = {xv0.comp, xv1.comp, xv2.comp, xv3.comp};  \
                _Pragma("unroll")                                              \
                for (int m = 0; m < 4; ++m) {                                  \
                    accA[m][0] = fmaf(xr[m], w0.x, accA[m][0]);                \
                    accA[m][1] = fmaf(xr[m], w0.y, accA[m][1]);                \
                    accA[m][2] = fmaf(xr[m], w0.z, accA[m][2]);                \
                    accB[m][0] = fmaf(xr[m], w1.x, accB[m][0]);                \
                    accB[m][1] = fmaf(xr[m], w1.y, accB[m][1]);                \
                    accB[m][2] = fmaf(xr[m], w1.z, accB[m][2]);                \
                    accB[m][3] = fmaf(xr[m], w1.w, accB[m][3]);                \
                    accA[m][3] = fmaf(xr[m], w0.w, accA[m][3]);                \
                }                                                              \
            }
            GSTEP(0, x) GSTEP(1, y) GSTEP(2, z) GSTEP(3, w)
#undef GSTEP
        }
        if (ch + 1 < NCH)
            *(float4*)&xs[b ^ 1][srow][skk] = nv;
        __syncthreads();
    }

#pragma unroll
    for (int m = 0; m < 4; ++m) {
        int row = r0 + r + 16 * m;
        if (row < n) {
            union { __half2 h[2]; uint2 u; } pa, pb;
            pa.h[0] = __floats2half2_rn(accA[m][0], accA[m][1]);
            pa.h[1] = __floats2half2_rn(accA[m][2], accA[m][3]);
            pb.h[0] = __floats2half2_rn(accB[m][0], accB[m][1]);
            pb.h[1] = __floats2half2_rn(accB[m][2], accB[m][3]);
            *(uint2*)&Y[(size_t)row * FDIM + 4 * c]      = pa.u;
            *(uint2*)&Y[(size_t)row * FDIM + 64 + 4 * c] = pb.u;
        }
    }
}

// ---------------------------------------------------------------------------
// Aggregation: half-wave (32 lanes x 4 fp16 feats) per node, 8 nodes/block.
// hw is fp16-packed; accumulate fp32; unroll 8 edges for MLP.
// ---------------------------------------------------------------------------
__device__ __forceinline__ void acc_edge(float4& a, uint2 v, float w) {
    __half2* h = (__half2*)&v;
    float2 f0 = __half22float2(h[0]);
    float2 f1 = __half22float2(h[1]);
    a.x = fmaf(w, f0.x, a.x);
    a.y = fmaf(w, f0.y, a.y);
    a.z = fmaf(w, f1.x, a.z);
    a.w = fmaf(w, f1.y, a.w);
}

__global__ __launch_bounds__(256) void aggregate_relu(
        const __half* __restrict__ hw, const int* __restrict__ rp,
        const int2* __restrict__ em, const float* __restrict__ dinv,
        const float* __restrict__ bias, float* __restrict__ out, int n) {
    const int lane = threadIdx.x & 31;
    const int node = blockIdx.x * 8 + (threadIdx.x >> 5);
    if (node >= n) return;
    const uint2* hw2 = (const uint2*)hw;
    int e0 = rp[node], e1 = rp[node + 1];
    float4 a{0.f, 0.f, 0.f, 0.f};
    int e = e0;
    for (; e + 8 <= e1; e += 8) {
        int2 m[8];
        uint2 v[8];
#pragma unroll
        for (int k = 0; k < 8; ++k) m[k] = em[e + k];
#pragma unroll
        for (int k = 0; k < 8; ++k) v[k] = hw2[(size_t)m[k].x * 32 + lane];
#pragma unroll
        for (int k = 0; k < 8; ++k) acc_edge(a, v[k], __int_as_float(m[k].y));
    }
    for (; e < e1; ++e) {
        int2 m = em[e];
        acc_edge(a, hw2[(size_t)m.x * 32 + lane], __int_as_float(m.y));
    }
    float dv = dinv[node];
    float sn = dv * dv;
    uint2 sv = hw2[(size_t)node * 32 + lane];
    __half2* sh = (__half2*)&sv;
    float2 s0 = __half22float2(sh[0]);
    float2 s1 = __half22float2(sh[1]);
    float4 b = ((const float4*)bias)[lane];
    a.x = fmaxf(fmaf(sn, s0.x, a.x) + b.x, 0.f);
    a.y = fmaxf(fmaf(sn, s0.y, a.y) + b.y, 0.f);
    a.z = fmaxf(fmaf(sn, s1.x, a.z) + b.z, 0.f);
    a.w = fmaxf(fmaf(sn, s1.y, a.w) + b.w, 0.f);
    ((float4*)out)[(size_t)node * 32 + lane] = a;
}

// Layer-2 aggregation fused with mean-pool accumulate (batch sorted: merge
// same-graph nodes in LDS first, ~1 atomic-set per block).
__global__ __launch_bounds__(256) void aggregate_pool(
        const __half* __restrict__ hw, const int* __restrict__ rp,
        const int2* __restrict__ em, const float* __restrict__ dinv,
        const float* __restrict__ bias, const int* __restrict__ batch,
        float* __restrict__ pool, int n) {
    __shared__ float4 part[8][32];
    __shared__ int gs[8];
    const int lane = threadIdx.x & 31;
    const int half = threadIdx.x >> 5;
    const int node = blockIdx.x * 8 + half;
    const bool valid = node < n;
    const uint2* hw2 = (const uint2*)hw;
    int e0 = 0, e1 = 0;
    if (valid) { e0 = rp[node]; e1 = rp[node + 1]; }
    float4 a{0.f, 0.f, 0.f, 0.f};
    int e = e0;
    for (; e + 8 <= e1; e += 8) {
        int2 m[8];
        uint2 v[8];
#pragma unroll
        for (int k = 0; k < 8; ++k) m[k] = em[e + k];
#pragma unroll
        for (int k = 0; k < 8; ++k) v[k] = hw2[(size_t)m[k].x * 32 + lane];
#pragma unroll
        for (int k = 0; k < 8; ++k) acc_edge(a, v[k], __int_as_float(m[k].y));
    }
    for (; e < e1; ++e) {
        int2 m = em[e];
        acc_edge(a, hw2[(size_t)m.x * 32 + lane], __int_as_float(m.y));
    }
    if (valid) {
        float dv = dinv[node];
        float sn = dv * dv;
        uint2 sv = hw2[(size_t)node * 32 + lane];
        __half2* sh = (__half2*)&sv;
        float2 s0 = __half22float2(sh[0]);
        float2 s1 = __half22float2(sh[1]);
        float4 b = ((const float4*)bias)[lane];
        a.x = fmaf(sn, s0.x, a.x) + b.x;
        a.y = fmaf(sn, s0.y, a.y) + b.y;
        a.z = fmaf(sn, s1.x, a.z) + b.z;
        a.w = fmaf(sn, s1.y, a.w) + b.w;
    }
    part[half][lane] = a;
    if (lane == 0) gs[half] = valid ? batch[node] : -1;
    __syncthreads();
    if (half == 0) {
        float4 acc = part[0][lane];
        int g0 = gs[0];
#pragma unroll
        for (int h = 1; h < 8; ++h) {
            if (gs[h] == g0) {
                float4 p = part[h][lane];
                acc.x += p.x; acc.y += p.y; acc.z += p.z; acc.w += p.w;
            } else {
                if (g0 >= 0) {
                    float* dst = &pool[g0 * FDIM + lane * 4];
                    atomicAdd(dst + 0, acc.x); atomicAdd(dst + 1, acc.y);
                    atomicAdd(dst + 2, acc.z); atomicAdd(dst + 3, acc.w);
                }
                g0 = gs[h];
                acc = part[h][lane];
            }
        }
        if (g0 >= 0) {
            float* dst = &pool[g0 * FDIM + lane * 4];
            atomicAdd(dst + 0, acc.x); atomicAdd(dst + 1, acc.y);
            atomicAdd(dst + 2, acc.z); atomicAdd(dst + 3, acc.w);
        }
    }
}

__global__ void pool_div(float* __restrict__ out, const int* __restrict__ gcnt, int total) {
    int i = blockIdx.x * blockDim.x + threadIdx.x;
    if (i < total) {
        int g = i >> 7;
        out[i] /= fmaxf((float)gcnt[g], 1.0f);
    }
}

// ---------------------------------------------------------------------------

extern "C" void kernel_launch(void* const* d_in, const int* in_sizes, int n_in,
                              void* d_out, int out_size, void* d_ws, size_t ws_size,
                              hipStream_t stream) {
    const float* x     = (const float*)d_in[0];
    const int*   ei    = (const int*)d_in[1];
    const int*   batch = (const int*)d_in[2];
    const float* W1    = (const float*)d_in[3];
    const float* b1    = (const float*)d_in[4];
    const float* W2    = (const float*)d_in[5];
    const float* b2    = (const float*)d_in[6];
    float* out = (float*)d_out;

    const int N = in_sizes[0] / FDIM;      // 100000
    const int E = in_sizes[1] / 2;         // 1600000
    const int G = out_size / FDIM;         // 1000
    const int* src = ei;
    const int* dst = ei + E;

    char* p = (char*)d_ws;
    auto alloc = [&](size_t bytes) {
        void* r = (void*)p;
        p += (bytes + 255) & ~(size_t)255;
        return r;
    };
    float*  dinv = (float*) alloc((size_t)N * 4);
    int*    cnt  = (int*)   alloc((size_t)N * 4);
    int*    rp   = (int*)   alloc((size_t)(N + 1) * 4);
    int*    fill = (int*)   alloc((size_t)N * 4);
    int*    bsum = (int*)   alloc(128 * 4);
    int*    gcnt = (int*)   alloc((size_t)G * 4);
    int2*   em   = (int2*)  alloc((size_t)E * 8);
    __half* hw   = (__half*)alloc((size_t)N * FDIM * 2);
    float*  h1   = (float*) alloc((size_t)N * FDIM * 4);

    hipMemsetAsync(cnt, 0, (size_t)N * 4, stream);
    hipMemsetAsync(gcnt, 0, (size_t)G * 4, stream);
    hipMemsetAsync(out, 0, (size_t)G * FDIM * 4, stream);

    const int NB = (N + 1023) / 1024;

    count_dst<<<2048, 256, 0, stream>>>(dst, cnt, E);
    compute_dinv<<<(N + 255) / 256, 256, 0, stream>>>(cnt, dinv, N);
    scan1<<<NB, 1024, 0, stream>>>(cnt, rp, bsum, N);
    scan2<<<1, 128, 0, stream>>>(bsum, NB);
    scan3<<<(N + 255) / 256, 256, 0, stream>>>(rp, fill, bsum, N, E);
    fill_csr<<<2048, 256, 0, stream>>>(src, dst, dinv, fill, em, E);
    graph_counts<<<(N + 255) / 256, 256, 0, stream>>>(batch, gcnt, N);

    const int GB = (N + BROWS - 1) / BROWS;
    // layer 1
    gemm128<<<GB, 256, 0, stream>>>(x, W1, hw, N);
    aggregate_relu<<<(N + 7) / 8, 256, 0, stream>>>(hw, rp, em, dinv, b1, h1, N);
    // layer 2 (+ fused pool)
    gemm128<<<GB, 256, 0, stream>>>(h1, W2, hw, N);
    aggregate_pool<<<(N + 7) / 8, 256, 0, stream>>>(hw, rp, em, dinv, b2, batch, out, N);
    pool_div<<<(G * FDIM + 255) / 256, 256, 0, stream>>>(out, gcnt, G * FDIM);
}

// Round 4
// 473.351 us; speedup vs baseline: 2.0133x; 1.1987x over previous
//
#include <hip/hip_runtime.h>
#include <hip/hip_fp16.h>

// N=100000 nodes, E=1600000 edges, F=128, G=1000 graphs.
#define FDIM 128
#define BROWS 64
#define KCH 16
#define NCH (FDIM / KCH)   // 8 chunks
#define BSHIFT 9           // 512 nodes per bucket
#define BNODES 512
#define EPB 4096           // edges per binscatter block

// ---------------------------------------------------------------------------
// CSR build via two-level bucket binning (write-locality aware).
// ---------------------------------------------------------------------------

__global__ __launch_bounds__(256) void bucket_count(const int* __restrict__ dst,
                                                    int* __restrict__ bcnt, int E) {
    __shared__ int lc[256];
    lc[threadIdx.x] = 0;
    __syncthreads();
    for (int e = blockIdx.x * blockDim.x + threadIdx.x; e < E;
         e += gridDim.x * blockDim.x)
        atomicAdd(&lc[dst[e] >> BSHIFT], 1);
    __syncthreads();
    int c = lc[threadIdx.x];
    if (c) atomicAdd(&bcnt[threadIdx.x], c);
}

// single block: exclusive scan of bucket counts -> bbase, bcur; rp[n]=E.
__global__ void bucket_scan(const int* __restrict__ bcnt, int* __restrict__ bbase,
                            int* __restrict__ bcur, int* __restrict__ rp,
                            int E, int n, int nbuck) {
    __shared__ int s[2][256];
    int t = threadIdx.x;
    int v = (t < nbuck) ? bcnt[t] : 0;
    s[0][t] = v;
    __syncthreads();
    int cur = 0;
    for (int off = 1; off < 256; off <<= 1) {
        int x = s[cur][t];
        if (t >= off) x += s[cur][t - off];
        s[cur ^ 1][t] = x;
        cur ^= 1;
        __syncthreads();
    }
    int ex = s[cur][t] - v;
    if (t < nbuck) { bbase[t] = ex; bcur[t] = ex; }
    if (t == 0) { bbase[nbuck] = E; rp[n] = E; }
}

// Bin edges into bucket-ordered buffer eb[] with block-contiguous runs.
__global__ __launch_bounds__(256) void binscatter(const int* __restrict__ src,
                                                  const int* __restrict__ dst,
                                                  int* __restrict__ bcur,
                                                  int2* __restrict__ eb, int E) {
    __shared__ int lcnt[256];
    __shared__ int gb[256];
    const int t = threadIdx.x;
    const int e0 = blockIdx.x * EPB;
    const int e1 = min(e0 + EPB, E);
    lcnt[t] = 0;
    __syncthreads();
    for (int e = e0 + t; e < e1; e += 256)
        atomicAdd(&lcnt[dst[e] >> BSHIFT], 1);
    __syncthreads();
    int c = lcnt[t];
    if (c) gb[t] = atomicAdd(&bcur[t], c);   // claim contiguous run per bucket
    __syncthreads();
    lcnt[t] = 0;
    __syncthreads();
    for (int e = e0 + t; e < e1; e += 256) {
        int d = dst[e];
        int b = d >> BSHIFT;
        int lo = atomicAdd(&lcnt[b], 1);
        eb[gb[b] + lo] = make_int2(src[e], d);
    }
}

// One block per bucket: per-node degree + exclusive scan in LDS -> rp, dinv.
__global__ __launch_bounds__(256) void csr_count(const int2* __restrict__ eb,
                                                 const int* __restrict__ bbase,
                                                 int* __restrict__ rp,
                                                 float* __restrict__ dinv, int n) {
    __shared__ int lcnt[BNODES];
    __shared__ int s[2][BNODES];
    const int t = threadIdx.x;
    const int node0 = blockIdx.x << BSHIFT;
    const int nloc = min(BNODES, n - node0);
    lcnt[t] = 0; lcnt[t + 256] = 0;
    __syncthreads();
    const int eb0 = bbase[blockIdx.x], eb1 = bbase[blockIdx.x + 1];
    for (int e = eb0 + t; e < eb1; e += 256)
        atomicAdd(&lcnt[eb[e].y - node0], 1);
    __syncthreads();
    s[0][t] = lcnt[t]; s[0][t + 256] = lcnt[t + 256];
    __syncthreads();
    int cur = 0;
    for (int off = 1; off < BNODES; off <<= 1) {
        int x0 = s[cur][t];       if (t >= off)        x0 += s[cur][t - off];
        int x1 = s[cur][t + 256]; if (t + 256 >= off)  x1 += s[cur][t + 256 - off];
        s[cur ^ 1][t] = x0; s[cur ^ 1][t + 256] = x1;
        cur ^= 1;
        __syncthreads();
    }
    if (t < nloc) {
        rp[node0 + t] = eb0 + s[cur][t] - lcnt[t];
        dinv[node0 + t] = rsqrtf((float)lcnt[t] + 1.0f);
    }
    if (t + 256 < nloc) {
        rp[node0 + t + 256] = eb0 + s[cur][t + 256] - lcnt[t + 256];
        dinv[node0 + t + 256] = rsqrtf((float)lcnt[t + 256] + 1.0f);
    }
}

// One block per bucket: scatter (src, norm) into em; region exclusive to block.
__global__ __launch_bounds__(256) void csr_fill(const int2* __restrict__ eb,
                                                const int* __restrict__ bbase,
                                                const int* __restrict__ rp,
                                                const float* __restrict__ dinv,
                                                int2* __restrict__ em, int n) {
    __shared__ int lcur[BNODES];
    const int t = threadIdx.x;
    const int node0 = blockIdx.x << BSHIFT;
    const int nloc = min(BNODES, n - node0);
    if (t < nloc) lcur[t] = rp[node0 + t];
    if (t + 256 < nloc) lcur[t + 256] = rp[node0 + t + 256];
    __syncthreads();
    const int eb0 = bbase[blockIdx.x], eb1 = bbase[blockIdx.x + 1];
    for (int e = eb0 + t; e < eb1; e += 256) {
        int2 sd = eb[e];
        int pos = atomicAdd(&lcur[sd.y - node0], 1);
        em[pos] = make_int2(sd.x, __float_as_int(dinv[sd.x] * dinv[sd.y]));
    }
}

__global__ void graph_counts(const int* __restrict__ batch, int* __restrict__ gcnt, int n) {
    int i = blockIdx.x * blockDim.x + threadIdx.x;
    if (i < n) atomicAdd(&gcnt[batch[i]], 1);
}

// ---------------------------------------------------------------------------
// Register-blocked dense transform: Y16[n][128] = X[n][128] @ W[128][128],
// output packed fp16. Block: 256 thr, 64 rows x 128 cols; thread: 4x8.
// ---------------------------------------------------------------------------
__global__ __launch_bounds__(256) void gemm128(const float* __restrict__ X,
                                               const float* __restrict__ W,
                                               __half* __restrict__ Y, int n) {
    __shared__ float Ws[FDIM * FDIM];          // 64 KiB
    __shared__ float xs[2][BROWS][KCH + 4];    // 10 KiB

    const int tid  = threadIdx.x;
    const int c    = tid & 15;
    const int r    = tid >> 4;
    const int srow = tid >> 2;
    const int skk  = (tid & 3) << 2;
    const int r0   = blockIdx.x * BROWS;

    for (int i = tid; i < FDIM * FDIM; i += 256) Ws[i] = W[i];

    const int grow  = r0 + srow;
    const bool rowok = grow < n;
    const float* xrow = X + (size_t)grow * FDIM + skk;

    float4 v = rowok ? *(const float4*)xrow : float4{0.f, 0.f, 0.f, 0.f};
    *(float4*)&xs[0][srow][skk] = v;
    __syncthreads();

    float accA[4][4], accB[4][4];
#pragma unroll
    for (int m = 0; m < 4; ++m)
#pragma unroll
        for (int i = 0; i < 4; ++i) { accA[m][i] = 0.f; accB[m][i] = 0.f; }

    for (int ch = 0; ch < NCH; ++ch) {
        const int b = ch & 1;
        float4 nv{0.f, 0.f, 0.f, 0.f};
        if (ch + 1 < NCH && rowok)
            nv = *(const float4*)(xrow + (ch + 1) * KCH);
        const int k0 = ch * KCH;
#pragma unroll
        for (int k4 = 0; k4 < KCH; k4 += 4) {
            float4 xv0 = *(const float4*)&xs[b][r][k4];
            float4 xv1 = *(const float4*)&xs[b][r + 16][k4];
            float4 xv2 = *(const float4*)&xs[b][r + 32][k4];
            float4 xv3 = *(const float4*)&xs[b][r + 48][k4];
#define GSTEP(kk, comp)                                                        \
            {                                                                  \
                const float* wp = &Ws[(k0 + k4 + kk) * FDIM + 4 * c];          \
                const float4 w0 = *(const float4*)wp;                          \
                const float4 w1 = *(const float4*)(wp + 64);                   \
                const float xr[4] = {xv0.comp, xv1.comp, xv2.comp, xv3.comp};  \
                _Pragma("unroll")                                              \
                for (int m = 0; m < 4; ++m) {                                  \
                    accA[m][0] = fmaf(xr[m], w0.x, accA[m][0]);                \
                    accA[m][1] = fmaf(xr[m], w0.y, accA[m][1]);                \
                    accA[m][2] = fmaf(xr[m], w0.z, accA[m][2]);                \
                    accB[m][0] = fmaf(xr[m], w1.x, accB[m][0]);                \
                    accB[m][1] = fmaf(xr[m], w1.y, accB[m][1]);                \
                    accB[m][2] = fmaf(xr[m], w1.z, accB[m][2]);                \
                    accB[m][3] = fmaf(xr[m], w1.w, accB[m][3]);                \
                    accA[m][3] = fmaf(xr[m], w0.w, accA[m][3]);                \
                }                                                              \
            }
            GSTEP(0, x) GSTEP(1, y) GSTEP(2, z) GSTEP(3, w)
#undef GSTEP
        }
        if (ch + 1 < NCH)
            *(float4*)&xs[b ^ 1][srow][skk] = nv;
        __syncthreads();
    }

#pragma unroll
    for (int m = 0; m < 4; ++m) {
        int row = r0 + r + 16 * m;
        if (row < n) {
            union { __half2 h[2]; uint2 u; } pa, pb;
            pa.h[0] = __floats2half2_rn(accA[m][0], accA[m][1]);
            pa.h[1] = __floats2half2_rn(accA[m][2], accA[m][3]);
            pb.h[0] = __floats2half2_rn(accB[m][0], accB[m][1]);
            pb.h[1] = __floats2half2_rn(accB[m][2], accB[m][3]);
            *(uint2*)&Y[(size_t)row * FDIM + 4 * c]      = pa.u;
            *(uint2*)&Y[(size_t)row * FDIM + 64 + 4 * c] = pb.u;
        }
    }
}

// ---------------------------------------------------------------------------
// Aggregation: half-wave (32 lanes x 4 fp16 feats) per node, 8 nodes/block.
// ---------------------------------------------------------------------------
__device__ __forceinline__ void acc_edge(float4& a, uint2 v, float w) {
    __half2* h = (__half2*)&v;
    float2 f0 = __half22float2(h[0]);
    float2 f1 = __half22float2(h[1]);
    a.x = fmaf(w, f0.x, a.x);
    a.y = fmaf(w, f0.y, a.y);
    a.z = fmaf(w, f1.x, a.z);
    a.w = fmaf(w, f1.y, a.w);
}

__global__ __launch_bounds__(256) void aggregate_relu(
        const __half* __restrict__ hw, const int* __restrict__ rp,
        const int2* __restrict__ em, const float* __restrict__ dinv,
        const float* __restrict__ bias, float* __restrict__ out, int n) {
    const int lane = threadIdx.x & 31;
    const int node = blockIdx.x * 8 + (threadIdx.x >> 5);
    if (node >= n) return;
    const uint2* hw2 = (const uint2*)hw;
    int e0 = rp[node], e1 = rp[node + 1];
    float4 a{0.f, 0.f, 0.f, 0.f};
    int e = e0;
    for (; e + 8 <= e1; e += 8) {
        int2 m[8];
        uint2 v[8];
#pragma unroll
        for (int k = 0; k < 8; ++k) m[k] = em[e + k];
#pragma unroll
        for (int k = 0; k < 8; ++k) v[k] = hw2[(size_t)m[k].x * 32 + lane];
#pragma unroll
        for (int k = 0; k < 8; ++k) acc_edge(a, v[k], __int_as_float(m[k].y));
    }
    for (; e < e1; ++e) {
        int2 m = em[e];
        acc_edge(a, hw2[(size_t)m.x * 32 + lane], __int_as_float(m.y));
    }
    float dv = dinv[node];
    float sn = dv * dv;
    uint2 sv = hw2[(size_t)node * 32 + lane];
    __half2* sh = (__half2*)&sv;
    float2 s0 = __half22float2(sh[0]);
    float2 s1 = __half22float2(sh[1]);
    float4 b = ((const float4*)bias)[lane];
    a.x = fmaxf(fmaf(sn, s0.x, a.x) + b.x, 0.f);
    a.y = fmaxf(fmaf(sn, s0.y, a.y) + b.y, 0.f);
    a.z = fmaxf(fmaf(sn, s1.x, a.z) + b.z, 0.f);
    a.w = fmaxf(fmaf(sn, s1.y, a.w) + b.w, 0.f);
    ((float4*)out)[(size_t)node * 32 + lane] = a;
}

// Layer-2 aggregation fused with mean-pool accumulate (batch sorted: merge
// same-graph nodes in LDS first, ~1 atomic-set per block).
__global__ __launch_bounds__(256) void aggregate_pool(
        const __half* __restrict__ hw, const int* __restrict__ rp,
        const int2* __restrict__ em, const float* __restrict__ dinv,
        const float* __restrict__ bias, const int* __restrict__ batch,
        float* __restrict__ pool, int n) {
    __shared__ float4 part[8][32];
    __shared__ int gs[8];
    const int lane = threadIdx.x & 31;
    const int half = threadIdx.x >> 5;
    const int node = blockIdx.x * 8 + half;
    const bool valid = node < n;
    const uint2* hw2 = (const uint2*)hw;
    int e0 = 0, e1 = 0;
    if (valid) { e0 = rp[node]; e1 = rp[node + 1]; }
    float4 a{0.f, 0.f, 0.f, 0.f};
    int e = e0;
    for (; e + 8 <= e1; e += 8) {
        int2 m[8];
        uint2 v[8];
#pragma unroll
        for (int k = 0; k < 8; ++k) m[k] = em[e + k];
#pragma unroll
        for (int k = 0; k < 8; ++k) v[k] = hw2[(size_t)m[k].x * 32 + lane];
#pragma unroll
        for (int k = 0; k < 8; ++k) acc_edge(a, v[k], __int_as_float(m[k].y));
    }
    for (; e < e1; ++e) {
        int2 m = em[e];
        acc_edge(a, hw2[(size_t)m.x * 32 + lane], __int_as_float(m.y));
    }
    if (valid) {
        float dv = dinv[node];
        float sn = dv * dv;
        uint2 sv = hw2[(size_t)node * 32 + lane];
        __half2* sh = (__half2*)&sv;
        float2 s0 = __half22float2(sh[0]);
        float2 s1 = __half22float2(sh[1]);
        float4 b = ((const float4*)bias)[lane];
        a.x = fmaf(sn, s0.x, a.x) + b.x;
        a.y = fmaf(sn, s0.y, a.y) + b.y;
        a.z = fmaf(sn, s1.x, a.z) + b.z;
        a.w = fmaf(sn, s1.y, a.w) + b.w;
    }
    part[half][lane] = a;
    if (lane == 0) gs[half] = valid ? batch[node] : -1;
    __syncthreads();
    if (half == 0) {
        float4 acc = part[0][lane];
        int g0 = gs[0];
#pragma unroll
        for (int h = 1; h < 8; ++h) {
            if (gs[h] == g0) {
                float4 p = part[h][lane];
                acc.x += p.x; acc.y += p.y; acc.z += p.z; acc.w += p.w;
            } else {
                if (g0 >= 0) {
                    float* dst = &pool[g0 * FDIM + lane * 4];
                    atomicAdd(dst + 0, acc.x); atomicAdd(dst + 1, acc.y);
                    atomicAdd(dst + 2, acc.z); atomicAdd(dst + 3, acc.w);
                }
                g0 = gs[h];
                acc = part[h][lane];
            }
        }
        if (g0 >= 0) {
            float* dst = &pool[g0 * FDIM + lane * 4];
            atomicAdd(dst + 0, acc.x); atomicAdd(dst + 1, acc.y);
            atomicAdd(dst + 2, acc.z); atomicAdd(dst + 3, acc.w);
        }
    }
}

__global__ void pool_div(float* __restrict__ out, const int* __restrict__ gcnt, int total) {
    int i = blockIdx.x * blockDim.x + threadIdx.x;
    if (i < total) {
        int g = i >> 7;
        out[i] /= fmaxf((float)gcnt[g], 1.0f);
    }
}

// ---------------------------------------------------------------------------

extern "C" void kernel_launch(void* const* d_in, const int* in_sizes, int n_in,
                              void* d_out, int out_size, void* d_ws, size_t ws_size,
                              hipStream_t stream) {
    const float* x     = (const float*)d_in[0];
    const int*   ei    = (const int*)d_in[1];
    const int*   batch = (const int*)d_in[2];
    const float* W1    = (const float*)d_in[3];
    const float* b1    = (const float*)d_in[4];
    const float* W2    = (const float*)d_in[5];
    const float* b2    = (const float*)d_in[6];
    float* out = (float*)d_out;

    const int N = in_sizes[0] / FDIM;      // 100000
    const int E = in_sizes[1] / 2;         // 1600000
    const int G = out_size / FDIM;         // 1000
    const int* src = ei;
    const int* dst = ei + E;
    const int nbuck = (N + BNODES - 1) >> BSHIFT;   // 196

    char* p = (char*)d_ws;
    auto alloc = [&](size_t bytes) {
        void* r = (void*)p;
        p += (bytes + 255) & ~(size_t)255;
        return r;
    };
    float*  dinv  = (float*) alloc((size_t)N * 4);
    int*    rp    = (int*)   alloc((size_t)(N + 1) * 4);
    int*    gcnt  = (int*)   alloc((size_t)G * 4);
    int*    bcnt  = (int*)   alloc(256 * 4);
    int*    bbase = (int*)   alloc(257 * 4);
    int*    bcur  = (int*)   alloc(256 * 4);
    int2*   eb    = (int2*)  alloc((size_t)E * 8);
    int2*   em    = (int2*)  alloc((size_t)E * 8);
    __half* hw    = (__half*)alloc((size_t)N * FDIM * 2);
    float*  h1    = (float*) alloc((size_t)N * FDIM * 4);

    hipMemsetAsync(bcnt, 0, 256 * 4, stream);
    hipMemsetAsync(gcnt, 0, (size_t)G * 4, stream);
    hipMemsetAsync(out, 0, (size_t)G * FDIM * 4, stream);

    // CSR build
    bucket_count<<<1024, 256, 0, stream>>>(dst, bcnt, E);
    bucket_scan<<<1, 256, 0, stream>>>(bcnt, bbase, bcur, rp, E, N, nbuck);
    binscatter<<<(E + EPB - 1) / EPB, 256, 0, stream>>>(src, dst, bcur, eb, E);
    csr_count<<<nbuck, 256, 0, stream>>>(eb, bbase, rp, dinv, N);
    csr_fill<<<nbuck, 256, 0, stream>>>(eb, bbase, rp, dinv, em, N);
    graph_counts<<<(N + 255) / 256, 256, 0, stream>>>(batch, gcnt, N);

    const int GB = (N + BROWS - 1) / BROWS;
    // layer 1
    gemm128<<<GB, 256, 0, stream>>>(x, W1, hw, N);
    aggregate_relu<<<(N + 7) / 8, 256, 0, stream>>>(hw, rp, em, dinv, b1, h1, N);
    // layer 2 (+ fused pool)
    gemm128<<<GB, 256, 0, stream>>>(h1, W2, hw, N);
    aggregate_pool<<<(N + 7) / 8, 256, 0, stream>>>(hw, rp, em, dinv, b2, batch, out, N);
    pool_div<<<(G * FDIM + 255) / 256, 256, 0, stream>>>(out, gcnt, G * FDIM);
}

// Round 5
// 433.664 us; speedup vs baseline: 2.1975x; 1.0915x over previous
//
#include <hip/hip_runtime.h>
#include <hip/hip_fp16.h>

// N=100000 nodes, E=1600000 edges, F=128, G=1000 graphs.
#define FDIM 128
#define BROWS 64
#define KCH 16
#define NCH (FDIM / KCH)   // 8 chunks
#define BSHIFT 9           // 512 nodes per bucket
#define BNODES 512
#define EPB 4096           // edges per binscatter block

// ---------------------------------------------------------------------------
// CSR build via two-level bucket binning (write-locality aware).
// ---------------------------------------------------------------------------

__global__ __launch_bounds__(256) void bucket_count(const int* __restrict__ dst,
                                                    int* __restrict__ bcnt, int E) {
    __shared__ int lc[256];
    lc[threadIdx.x] = 0;
    __syncthreads();
    for (int e = blockIdx.x * blockDim.x + threadIdx.x; e < E;
         e += gridDim.x * blockDim.x)
        atomicAdd(&lc[dst[e] >> BSHIFT], 1);
    __syncthreads();
    int c = lc[threadIdx.x];
    if (c) atomicAdd(&bcnt[threadIdx.x], c);
}

// single block: exclusive scan of bucket counts -> bbase, bcur; rp[n]=E.
__global__ void bucket_scan(const int* __restrict__ bcnt, int* __restrict__ bbase,
                            int* __restrict__ bcur, int* __restrict__ rp,
                            int E, int n, int nbuck) {
    __shared__ int s[2][256];
    int t = threadIdx.x;
    int v = (t < nbuck) ? bcnt[t] : 0;
    s[0][t] = v;
    __syncthreads();
    int cur = 0;
    for (int off = 1; off < 256; off <<= 1) {
        int x = s[cur][t];
        if (t >= off) x += s[cur][t - off];
        s[cur ^ 1][t] = x;
        cur ^= 1;
        __syncthreads();
    }
    int ex = s[cur][t] - v;
    if (t < nbuck) { bbase[t] = ex; bcur[t] = ex; }
    if (t == 0) { bbase[nbuck] = E; rp[n] = E; }
}

// Bin edges into bucket-ordered buffer eb[] with block-contiguous runs.
__global__ __launch_bounds__(256) void binscatter(const int* __restrict__ src,
                                                  const int* __restrict__ dst,
                                                  int* __restrict__ bcur,
                                                  int2* __restrict__ eb, int E) {
    __shared__ int lcnt[256];
    __shared__ int gb[256];
    const int t = threadIdx.x;
    const int e0 = blockIdx.x * EPB;
    const int e1 = min(e0 + EPB, E);
    lcnt[t] = 0;
    __syncthreads();
    for (int e = e0 + t; e < e1; e += 256)
        atomicAdd(&lcnt[dst[e] >> BSHIFT], 1);
    __syncthreads();
    int c = lcnt[t];
    if (c) gb[t] = atomicAdd(&bcur[t], c);   // claim contiguous run per bucket
    __syncthreads();
    lcnt[t] = 0;
    __syncthreads();
    for (int e = e0 + t; e < e1; e += 256) {
        int d = dst[e];
        int b = d >> BSHIFT;
        int lo = atomicAdd(&lcnt[b], 1);
        eb[gb[b] + lo] = make_int2(src[e], d);
    }
}

// One block per bucket: per-node degree + exclusive scan in LDS -> rp, dinv.
__global__ __launch_bounds__(256) void csr_count(const int2* __restrict__ eb,
                                                 const int* __restrict__ bbase,
                                                 int* __restrict__ rp,
                                                 float* __restrict__ dinv, int n) {
    __shared__ int lcnt[BNODES];
    __shared__ int s[2][BNODES];
    const int t = threadIdx.x;
    const int node0 = blockIdx.x << BSHIFT;
    const int nloc = min(BNODES, n - node0);
    lcnt[t] = 0; lcnt[t + 256] = 0;
    __syncthreads();
    const int eb0 = bbase[blockIdx.x], eb1 = bbase[blockIdx.x + 1];
    for (int e = eb0 + t; e < eb1; e += 256)
        atomicAdd(&lcnt[eb[e].y - node0], 1);
    __syncthreads();
    s[0][t] = lcnt[t]; s[0][t + 256] = lcnt[t + 256];
    __syncthreads();
    int cur = 0;
    for (int off = 1; off < BNODES; off <<= 1) {
        int x0 = s[cur][t];       if (t >= off)        x0 += s[cur][t - off];
        int x1 = s[cur][t + 256]; if (t + 256 >= off)  x1 += s[cur][t + 256 - off];
        s[cur ^ 1][t] = x0; s[cur ^ 1][t + 256] = x1;
        cur ^= 1;
        __syncthreads();
    }
    if (t < nloc) {
        rp[node0 + t] = eb0 + s[cur][t] - lcnt[t];
        dinv[node0 + t] = rsqrtf((float)lcnt[t] + 1.0f);
    }
    if (t + 256 < nloc) {
        rp[node0 + t + 256] = eb0 + s[cur][t + 256] - lcnt[t + 256];
        dinv[node0 + t + 256] = rsqrtf((float)lcnt[t + 256] + 1.0f);
    }
}

// One block per bucket: scatter (src, norm) into em; region exclusive to block.
__global__ __launch_bounds__(256) void csr_fill(const int2* __restrict__ eb,
                                                const int* __restrict__ bbase,
                                                const int* __restrict__ rp,
                                                const float* __restrict__ dinv,
                                                int2* __restrict__ em, int n) {
    __shared__ int lcur[BNODES];
    const int t = threadIdx.x;
    const int node0 = blockIdx.x << BSHIFT;
    const int nloc = min(BNODES, n - node0);
    if (t < nloc) lcur[t] = rp[node0 + t];
    if (t + 256 < nloc) lcur[t + 256] = rp[node0 + t + 256];
    __syncthreads();
    const int eb0 = bbase[blockIdx.x], eb1 = bbase[blockIdx.x + 1];
    for (int e = eb0 + t; e < eb1; e += 256) {
        int2 sd = eb[e];
        int pos = atomicAdd(&lcur[sd.y - node0], 1);
        em[pos] = make_int2(sd.x, __float_as_int(dinv[sd.x] * dinv[sd.y]));
    }
}

__global__ void graph_counts(const int* __restrict__ batch, int* __restrict__ gcnt, int n) {
    int i = blockIdx.x * blockDim.x + threadIdx.x;
    if (i < n) atomicAdd(&gcnt[batch[i]], 1);
}

// ---------------------------------------------------------------------------
// Register-blocked dense transform: Y16[n][128] = X[n][128] @ W[128][128],
// output packed fp16. Block: 256 thr, 64 rows x 128 cols; thread: 4x8.
// ---------------------------------------------------------------------------
__global__ __launch_bounds__(256) void gemm128(const float* __restrict__ X,
                                               const float* __restrict__ W,
                                               __half* __restrict__ Y, int n) {
    __shared__ float Ws[FDIM * FDIM];          // 64 KiB
    __shared__ float xs[2][BROWS][KCH + 4];    // 10 KiB

    const int tid  = threadIdx.x;
    const int c    = tid & 15;
    const int r    = tid >> 4;
    const int srow = tid >> 2;
    const int skk  = (tid & 3) << 2;
    const int r0   = blockIdx.x * BROWS;

    for (int i = tid; i < FDIM * FDIM; i += 256) Ws[i] = W[i];

    const int grow  = r0 + srow;
    const bool rowok = grow < n;
    const float* xrow = X + (size_t)grow * FDIM + skk;

    float4 v = rowok ? *(const float4*)xrow : float4{0.f, 0.f, 0.f, 0.f};
    *(float4*)&xs[0][srow][skk] = v;
    __syncthreads();

    float accA[4][4], accB[4][4];
#pragma unroll
    for (int m = 0; m < 4; ++m)
#pragma unroll
        for (int i = 0; i < 4; ++i) { accA[m][i] = 0.f; accB[m][i] = 0.f; }

    for (int ch = 0; ch < NCH; ++ch) {
        const int b = ch & 1;
        float4 nv{0.f, 0.f, 0.f, 0.f};
        if (ch + 1 < NCH && rowok)
            nv = *(const float4*)(xrow + (ch + 1) * KCH);
        const int k0 = ch * KCH;
#pragma unroll
        for (int k4 = 0; k4 < KCH; k4 += 4) {
            float4 xv0 = *(const float4*)&xs[b][r][k4];
            float4 xv1 = *(const float4*)&xs[b][r + 16][k4];
            float4 xv2 = *(const float4*)&xs[b][r + 32][k4];
            float4 xv3 = *(const float4*)&xs[b][r + 48][k4];
#define GSTEP(kk, comp)                                                        \
            {                                                                  \
                const float* wp = &Ws[(k0 + k4 + kk) * FDIM + 4 * c];          \
                const float4 w0 = *(const float4*)wp;                          \
                const float4 w1 = *(const float4*)(wp + 64);                   \
                const float xr[4] = {xv0.comp, xv1.comp, xv2.comp, xv3.comp};  \
                _Pragma("unroll")                                              \
                for (int m = 0; m < 4; ++m) {                                  \
                    accA[m][0] = fmaf(xr[m], w0.x, accA[m][0]);                \
                    accA[m][1] = fmaf(xr[m], w0.y, accA[m][1]);                \
                    accA[m][2] = fmaf(xr[m], w0.z, accA[m][2]);                \
                    accB[m][0] = fmaf(xr[m], w1.x, accB[m][0]);                \
                    accB[m][1] = fmaf(xr[m], w1.y, accB[m][1]);                \
                    accB[m][2] = fmaf(xr[m], w1.z, accB[m][2]);                \
                    accB[m][3] = fmaf(xr[m], w1.w, accB[m][3]);                \
                    accA[m][3] = fmaf(xr[m], w0.w, accA[m][3]);                \
                }                                                              \
            }
            GSTEP(0, x) GSTEP(1, y) GSTEP(2, z) GSTEP(3, w)
#undef GSTEP
        }
        if (ch + 1 < NCH)
            *(float4*)&xs[b ^ 1][srow][skk] = nv;
        __syncthreads();
    }

#pragma unroll
    for (int m = 0; m < 4; ++m) {
        int row = r0 + r + 16 * m;
        if (row < n) {
            union { __half2 h[2]; uint2 u; } pa, pb;
            pa.h[0] = __floats2half2_rn(accA[m][0], accA[m][1]);
            pa.h[1] = __floats2half2_rn(accA[m][2], accA[m][3]);
            pb.h[0] = __floats2half2_rn(accB[m][0], accB[m][1]);
            pb.h[1] = __floats2half2_rn(accB[m][2], accB[m][3]);
            *(uint2*)&Y[(size_t)row * FDIM + 4 * c]      = pa.u;
            *(uint2*)&Y[(size_t)row * FDIM + 64 + 4 * c] = pb.u;
        }
    }
}

// ---------------------------------------------------------------------------
// Aggregation: half-wave (32 lanes x 4 fp16 feats) per node, 8 nodes/block.
// ---------------------------------------------------------------------------
__device__ __forceinline__ void acc_edge(float4& a, uint2 v, float w) {
    __half2* h = (__half2*)&v;
    float2 f0 = __half22float2(h[0]);
    float2 f1 = __half22float2(h[1]);
    a.x = fmaf(w, f0.x, a.x);
    a.y = fmaf(w, f0.y, a.y);
    a.z = fmaf(w, f1.x, a.z);
    a.w = fmaf(w, f1.y, a.w);
}

// Layer 1: h1 = relu(agg(hw) + b1), h1 packed fp16.
__global__ __launch_bounds__(256) void aggregate_relu(
        const __half* __restrict__ hw, const int* __restrict__ rp,
        const int2* __restrict__ em, const float* __restrict__ dinv,
        const float* __restrict__ bias, __half* __restrict__ out, int n) {
    const int lane = threadIdx.x & 31;
    const int node = blockIdx.x * 8 + (threadIdx.x >> 5);
    if (node >= n) return;
    const uint2* hw2 = (const uint2*)hw;
    int e0 = rp[node], e1 = rp[node + 1];
    float4 a{0.f, 0.f, 0.f, 0.f};
    int e = e0;
    for (; e + 8 <= e1; e += 8) {
        int2 m[8];
        uint2 v[8];
#pragma unroll
        for (int k = 0; k < 8; ++k) m[k] = em[e + k];
#pragma unroll
        for (int k = 0; k < 8; ++k) v[k] = hw2[(size_t)m[k].x * 32 + lane];
#pragma unroll
        for (int k = 0; k < 8; ++k) acc_edge(a, v[k], __int_as_float(m[k].y));
    }
    for (; e < e1; ++e) {
        int2 m = em[e];
        acc_edge(a, hw2[(size_t)m.x * 32 + lane], __int_as_float(m.y));
    }
    float dv = dinv[node];
    float sn = dv * dv;
    uint2 sv = hw2[(size_t)node * 32 + lane];
    __half2* sh = (__half2*)&sv;
    float2 s0 = __half22float2(sh[0]);
    float2 s1 = __half22float2(sh[1]);
    float4 b = ((const float4*)bias)[lane];
    a.x = fmaxf(fmaf(sn, s0.x, a.x) + b.x, 0.f);
    a.y = fmaxf(fmaf(sn, s0.y, a.y) + b.y, 0.f);
    a.z = fmaxf(fmaf(sn, s1.x, a.z) + b.z, 0.f);
    a.w = fmaxf(fmaf(sn, s1.y, a.w) + b.w, 0.f);
    union { __half2 h[2]; uint2 u; } pk;
    pk.h[0] = __floats2half2_rn(a.x, a.y);
    pk.h[1] = __floats2half2_rn(a.z, a.w);
    ((uint2*)out)[(size_t)node * 32 + lane] = pk.u;
}

// Layer 2 (algebraic): pool(A(h1 W2)+b2) == (pool(A h1)) W2 + b2.
// This kernel computes pool(A h1): gather h1, LDS-merge by graph (batch is
// sorted), atomics into pool[G][128]. No W2, no bias here.
__global__ __launch_bounds__(256) void aggregate_pool(
        const __half* __restrict__ h1, const int* __restrict__ rp,
        const int2* __restrict__ em, const float* __restrict__ dinv,
        const int* __restrict__ batch, float* __restrict__ pool, int n) {
    __shared__ float4 part[8][32];
    __shared__ int gs[8];
    const int lane = threadIdx.x & 31;
    const int half = threadIdx.x >> 5;
    const int node = blockIdx.x * 8 + half;
    const bool valid = node < n;
    const uint2* hw2 = (const uint2*)h1;
    int e0 = 0, e1 = 0;
    if (valid) { e0 = rp[node]; e1 = rp[node + 1]; }
    float4 a{0.f, 0.f, 0.f, 0.f};
    int e = e0;
    for (; e + 8 <= e1; e += 8) {
        int2 m[8];
        uint2 v[8];
#pragma unroll
        for (int k = 0; k < 8; ++k) m[k] = em[e + k];
#pragma unroll
        for (int k = 0; k < 8; ++k) v[k] = hw2[(size_t)m[k].x * 32 + lane];
#pragma unroll
        for (int k = 0; k < 8; ++k) acc_edge(a, v[k], __int_as_float(m[k].y));
    }
    for (; e < e1; ++e) {
        int2 m = em[e];
        acc_edge(a, hw2[(size_t)m.x * 32 + lane], __int_as_float(m.y));
    }
    if (valid) {
        float dv = dinv[node];
        float sn = dv * dv;
        uint2 sv = hw2[(size_t)node * 32 + lane];
        __half2* sh = (__half2*)&sv;
        float2 s0 = __half22float2(sh[0]);
        float2 s1 = __half22float2(sh[1]);
        a.x = fmaf(sn, s0.x, a.x);
        a.y = fmaf(sn, s0.y, a.y);
        a.z = fmaf(sn, s1.x, a.z);
        a.w = fmaf(sn, s1.y, a.w);
    }
    part[half][lane] = a;
    if (lane == 0) gs[half] = valid ? batch[node] : -1;
    __syncthreads();
    if (half == 0) {
        float4 acc = part[0][lane];
        int g0 = gs[0];
#pragma unroll
        for (int h = 1; h < 8; ++h) {
            if (gs[h] == g0) {
                float4 p = part[h][lane];
                acc.x += p.x; acc.y += p.y; acc.z += p.z; acc.w += p.w;
            } else {
                if (g0 >= 0) {
                    float* dst = &pool[g0 * FDIM + lane * 4];
                    atomicAdd(dst + 0, acc.x); atomicAdd(dst + 1, acc.y);
                    atomicAdd(dst + 2, acc.z); atomicAdd(dst + 3, acc.w);
                }
                g0 = gs[h];
                acc = part[h][lane];
            }
        }
        if (g0 >= 0) {
            float* dst = &pool[g0 * FDIM + lane * 4];
            atomicAdd(dst + 0, acc.x); atomicAdd(dst + 1, acc.y);
            atomicAdd(dst + 2, acc.z); atomicAdd(dst + 3, acc.w);
        }
    }
}

// out[g] = (pool[g]/cnt[g]) @ W2 + b2   (b2 suppressed for empty graphs)
__global__ __launch_bounds__(256) void pool_gemm(const float* __restrict__ pool,
                                                 const int* __restrict__ gcnt,
                                                 const float* __restrict__ W2,
                                                 const float* __restrict__ b2,
                                                 float* __restrict__ out, int G) {
    __shared__ float Ws[FDIM * FDIM];   // 64 KiB
    __shared__ float row[2][FDIM];
    for (int i = threadIdx.x; i < FDIM * FDIM; i += 256) Ws[i] = W2[i];
    const int j  = threadIdx.x & 127;
    const int gh = threadIdx.x >> 7;
    for (int g0 = blockIdx.x * 2; g0 < G; g0 += gridDim.x * 2) {
        const int g = g0 + gh;
        __syncthreads();
        int c = 0;
        if (g < G) {
            c = gcnt[g];
            float inv = (c > 0) ? 1.0f / (float)c : 0.0f;
            row[gh][j] = pool[g * FDIM + j] * inv;
        }
        __syncthreads();
        if (g < G) {
            float acc = (c > 0) ? b2[j] : 0.0f;
#pragma unroll
            for (int k = 0; k < FDIM; ++k)
                acc = fmaf(row[gh][k], Ws[k * FDIM + j], acc);
            out[g * FDIM + j] = acc;
        }
    }
}

// ---------------------------------------------------------------------------

extern "C" void kernel_launch(void* const* d_in, const int* in_sizes, int n_in,
                              void* d_out, int out_size, void* d_ws, size_t ws_size,
                              hipStream_t stream) {
    const float* x     = (const float*)d_in[0];
    const int*   ei    = (const int*)d_in[1];
    const int*   batch = (const int*)d_in[2];
    const float* W1    = (const float*)d_in[3];
    const float* b1    = (const float*)d_in[4];
    const float* W2    = (const float*)d_in[5];
    const float* b2    = (const float*)d_in[6];
    float* out = (float*)d_out;

    const int N = in_sizes[0] / FDIM;      // 100000
    const int E = in_sizes[1] / 2;         // 1600000
    const int G = out_size / FDIM;         // 1000
    const int* src = ei;
    const int* dst = ei + E;
    const int nbuck = (N + BNODES - 1) >> BSHIFT;   // 196

    char* p = (char*)d_ws;
    auto alloc = [&](size_t bytes) {
        void* r = (void*)p;
        p += (bytes + 255) & ~(size_t)255;
        return r;
    };
    float*  dinv  = (float*) alloc((size_t)N * 4);
    int*    rp    = (int*)   alloc((size_t)(N + 1) * 4);
    int*    gcnt  = (int*)   alloc((size_t)G * 4);
    int*    bcnt  = (int*)   alloc(256 * 4);
    int*    bbase = (int*)   alloc(257 * 4);
    int*    bcur  = (int*)   alloc(256 * 4);
    int2*   eb    = (int2*)  alloc((size_t)E * 8);
    int2*   em    = (int2*)  alloc((size_t)E * 8);
    __half* hw    = (__half*)alloc((size_t)N * FDIM * 2);
    __half* h1    = (__half*)alloc((size_t)N * FDIM * 2);
    float*  pool  = (float*) alloc((size_t)G * FDIM * 4);

    hipMemsetAsync(bcnt, 0, 256 * 4, stream);
    hipMemsetAsync(gcnt, 0, (size_t)G * 4, stream);
    hipMemsetAsync(pool, 0, (size_t)G * FDIM * 4, stream);

    // CSR build
    bucket_count<<<1024, 256, 0, stream>>>(dst, bcnt, E);
    bucket_scan<<<1, 256, 0, stream>>>(bcnt, bbase, bcur, rp, E, N, nbuck);
    binscatter<<<(E + EPB - 1) / EPB, 256, 0, stream>>>(src, dst, bcur, eb, E);
    csr_count<<<nbuck, 256, 0, stream>>>(eb, bbase, rp, dinv, N);
    csr_fill<<<nbuck, 256, 0, stream>>>(eb, bbase, rp, dinv, em, N);
    graph_counts<<<(N + 255) / 256, 256, 0, stream>>>(batch, gcnt, N);

    const int GB = (N + BROWS - 1) / BROWS;
    // layer 1: hw = x@W1 (fp16), h1 = relu(agg(hw)+b1) (fp16)
    gemm128<<<GB, 256, 0, stream>>>(x, W1, hw, N);
    aggregate_relu<<<(N + 7) / 8, 256, 0, stream>>>(hw, rp, em, dinv, b1, h1, N);
    // layer 2: pool(A h1) -> [G,128], then micro-gemm with W2 + b2 + mean div
    aggregate_pool<<<(N + 7) / 8, 256, 0, stream>>>(h1, rp, em, dinv, batch, pool, N);
    pool_gemm<<<64, 256, 0, stream>>>(pool, gcnt, W2, b2, out, G);
}

// Round 6
// 409.971 us; speedup vs baseline: 2.3245x; 1.0578x over previous
//
#include <hip/hip_runtime.h>
#include <hip/hip_fp16.h>

// N=100000 nodes, E=1600000 edges, F=128, G=1000 graphs.
#define FDIM 128
#define BROWS 64
#define KCH 16
#define NCH (FDIM / KCH)   // 8 chunks
#define BSHIFT 9           // 512 nodes per bucket
#define BNODES 512
#define EPB 4096           // edges per binscatter block
// NOTE: u32 edge packing (src << 9 | dst&511) requires N < 2^23. N=100k ok.

// ---------------------------------------------------------------------------
// CSR build via two-level bucket binning (write-locality aware).
// ---------------------------------------------------------------------------

__global__ __launch_bounds__(256) void bucket_count(const int* __restrict__ dst,
                                                    int* __restrict__ bcnt, int E) {
    __shared__ int lc[256];
    lc[threadIdx.x] = 0;
    __syncthreads();
    for (int e = blockIdx.x * blockDim.x + threadIdx.x; e < E;
         e += gridDim.x * blockDim.x)
        atomicAdd(&lc[dst[e] >> BSHIFT], 1);
    __syncthreads();
    int c = lc[threadIdx.x];
    if (c) atomicAdd(&bcnt[threadIdx.x], c);
}

// single block: exclusive scan of bucket counts -> bbase, bcur; rp[n]=E.
__global__ void bucket_scan(const int* __restrict__ bcnt, int* __restrict__ bbase,
                            int* __restrict__ bcur, int* __restrict__ rp,
                            int E, int n, int nbuck) {
    __shared__ int s[2][256];
    int t = threadIdx.x;
    int v = (t < nbuck) ? bcnt[t] : 0;
    s[0][t] = v;
    __syncthreads();
    int cur = 0;
    for (int off = 1; off < 256; off <<= 1) {
        int x = s[cur][t];
        if (t >= off) x += s[cur][t - off];
        s[cur ^ 1][t] = x;
        cur ^= 1;
        __syncthreads();
    }
    int ex = s[cur][t] - v;
    if (t < nbuck) { bbase[t] = ex; bcur[t] = ex; }
    if (t == 0) { bbase[nbuck] = E; rp[n] = E; }
}

// Bin edges into bucket-ordered u32 buffer ebp[] with block-contiguous runs.
__global__ __launch_bounds__(256) void binscatter(const int* __restrict__ src,
                                                  const int* __restrict__ dst,
                                                  int* __restrict__ bcur,
                                                  unsigned* __restrict__ ebp, int E) {
    __shared__ int lcnt[256];
    __shared__ int gb[256];
    const int t = threadIdx.x;
    const int e0 = blockIdx.x * EPB;
    const int e1 = min(e0 + EPB, E);
    lcnt[t] = 0;
    __syncthreads();
    for (int e = e0 + t; e < e1; e += 256)
        atomicAdd(&lcnt[dst[e] >> BSHIFT], 1);
    __syncthreads();
    int c = lcnt[t];
    if (c) gb[t] = atomicAdd(&bcur[t], c);   // claim contiguous run per bucket
    __syncthreads();
    lcnt[t] = 0;
    __syncthreads();
    for (int e = e0 + t; e < e1; e += 256) {
        int d = dst[e];
        int b = d >> BSHIFT;
        int lo = atomicAdd(&lcnt[b], 1);
        ebp[gb[b] + lo] = ((unsigned)src[e] << BSHIFT) | (unsigned)(d & (BNODES - 1));
    }
}

// One block per bucket: degree count + LDS scan -> rp, dinv; then scatter
// src-only edge list em in CSR order; also graph-count histogram.
__global__ __launch_bounds__(256) void csr_build(const unsigned* __restrict__ ebp,
                                                 const int* __restrict__ bbase,
                                                 const int* __restrict__ batch,
                                                 int* __restrict__ rp,
                                                 float* __restrict__ dinv,
                                                 int* __restrict__ em,
                                                 int* __restrict__ gcnt, int n) {
    __shared__ int lcnt[BNODES];
    __shared__ int s[2][BNODES];
    __shared__ int lcur[BNODES];
    const int t = threadIdx.x;
    const int node0 = blockIdx.x << BSHIFT;
    const int nloc = min(BNODES, n - node0);
    lcnt[t] = 0; lcnt[t + 256] = 0;
    __syncthreads();
    const int eb0 = bbase[blockIdx.x], eb1 = bbase[blockIdx.x + 1];
    for (int e = eb0 + t; e < eb1; e += 256)
        atomicAdd(&lcnt[ebp[e] & (BNODES - 1)], 1);
    __syncthreads();
    s[0][t] = lcnt[t]; s[0][t + 256] = lcnt[t + 256];
    __syncthreads();
    int cur = 0;
    for (int off = 1; off < BNODES; off <<= 1) {
        int x0 = s[cur][t];       if (t >= off)       x0 += s[cur][t - off];
        int x1 = s[cur][t + 256]; if (t + 256 >= off) x1 += s[cur][t + 256 - off];
        s[cur ^ 1][t] = x0; s[cur ^ 1][t + 256] = x1;
        cur ^= 1;
        __syncthreads();
    }
    int ex0 = eb0 + s[cur][t] - lcnt[t];
    int ex1 = eb0 + s[cur][t + 256] - lcnt[t + 256];
    lcur[t] = ex0; lcur[t + 256] = ex1;
    if (t < nloc) {
        rp[node0 + t] = ex0;
        dinv[node0 + t] = rsqrtf((float)lcnt[t] + 1.0f);
    }
    if (t + 256 < nloc) {
        rp[node0 + t + 256] = ex1;
        dinv[node0 + t + 256] = rsqrtf((float)lcnt[t + 256] + 1.0f);
    }
    __syncthreads();
    for (int e = eb0 + t; e < eb1; e += 256) {
        unsigned v = ebp[e];
        int pos = atomicAdd(&lcur[v & (BNODES - 1)], 1);
        em[pos] = (int)(v >> BSHIFT);
    }
    if (t < nloc) atomicAdd(&gcnt[batch[node0 + t]], 1);
    if (t + 256 < nloc) atomicAdd(&gcnt[batch[node0 + t + 256]], 1);
}

// ---------------------------------------------------------------------------
// Register-blocked dense transform with row scaling:
//   Y16[r][128] = dinv[r] * (X[r][128] @ W[128][128]), packed fp16.
// ---------------------------------------------------------------------------
__global__ __launch_bounds__(256) void gemm128(const float* __restrict__ X,
                                               const float* __restrict__ W,
                                               const float* __restrict__ dinv,
                                               __half* __restrict__ Y, int n) {
    __shared__ float Ws[FDIM * FDIM];          // 64 KiB
    __shared__ float xs[2][BROWS][KCH + 4];    // 10 KiB

    const int tid  = threadIdx.x;
    const int c    = tid & 15;
    const int r    = tid >> 4;
    const int srow = tid >> 2;
    const int skk  = (tid & 3) << 2;
    const int r0   = blockIdx.x * BROWS;

    for (int i = tid; i < FDIM * FDIM; i += 256) Ws[i] = W[i];

    const int grow  = r0 + srow;
    const bool rowok = grow < n;
    const float* xrow = X + (size_t)grow * FDIM + skk;

    float4 v = rowok ? *(const float4*)xrow : float4{0.f, 0.f, 0.f, 0.f};
    *(float4*)&xs[0][srow][skk] = v;
    __syncthreads();

    float accA[4][4], accB[4][4];
#pragma unroll
    for (int m = 0; m < 4; ++m)
#pragma unroll
        for (int i = 0; i < 4; ++i) { accA[m][i] = 0.f; accB[m][i] = 0.f; }

    for (int ch = 0; ch < NCH; ++ch) {
        const int b = ch & 1;
        float4 nv{0.f, 0.f, 0.f, 0.f};
        if (ch + 1 < NCH && rowok)
            nv = *(const float4*)(xrow + (ch + 1) * KCH);
        const int k0 = ch * KCH;
#pragma unroll
        for (int k4 = 0; k4 < KCH; k4 += 4) {
            float4 xv0 = *(const float4*)&xs[b][r][k4];
            float4 xv1 = *(const float4*)&xs[b][r + 16][k4];
            float4 xv2 = *(const float4*)&xs[b][r + 32][k4];
            float4 xv3 = *(const float4*)&xs[b][r + 48][k4];
#define GSTEP(kk, comp)                                                        \
            {                                                                  \
                const float* wp = &Ws[(k0 + k4 + kk) * FDIM + 4 * c];          \
                const float4 w0 = *(const float4*)wp;                          \
                const float4 w1 = *(const float4*)(wp + 64);                   \
                const float xr[4] = {xv0.comp, xv1.comp, xv2.comp, xv3.comp};  \
                _Pragma("unroll")                                              \
                for (int m = 0; m < 4; ++m) {                                  \
                    accA[m][0] = fmaf(xr[m], w0.x, accA[m][0]);                \
                    accA[m][1] = fmaf(xr[m], w0.y, accA[m][1]);                \
                    accA[m][2] = fmaf(xr[m], w0.z, accA[m][2]);                \
                    accB[m][0] = fmaf(xr[m], w1.x, accB[m][0]);                \
                    accB[m][1] = fmaf(xr[m], w1.y, accB[m][1]);                \
                    accB[m][2] = fmaf(xr[m], w1.z, accB[m][2]);                \
                    accB[m][3] = fmaf(xr[m], w1.w, accB[m][3]);                \
                    accA[m][3] = fmaf(xr[m], w0.w, accA[m][3]);                \
                }                                                              \
            }
            GSTEP(0, x) GSTEP(1, y) GSTEP(2, z) GSTEP(3, w)
#undef GSTEP
        }
        if (ch + 1 < NCH)
            *(float4*)&xs[b ^ 1][srow][skk] = nv;
        __syncthreads();
    }

#pragma unroll
    for (int m = 0; m < 4; ++m) {
        int row = r0 + r + 16 * m;
        if (row < n) {
            float dv = dinv[row];
            union { __half2 h[2]; uint2 u; } pa, pb;
            pa.h[0] = __floats2half2_rn(dv * accA[m][0], dv * accA[m][1]);
            pa.h[1] = __floats2half2_rn(dv * accA[m][2], dv * accA[m][3]);
            pb.h[0] = __floats2half2_rn(dv * accB[m][0], dv * accB[m][1]);
            pb.h[1] = __floats2half2_rn(dv * accB[m][2], dv * accB[m][3]);
            *(uint2*)&Y[(size_t)row * FDIM + 4 * c]      = pa.u;
            *(uint2*)&Y[(size_t)row * FDIM + 64 + 4 * c] = pb.u;
        }
    }
}

// ---------------------------------------------------------------------------
// Aggregation: half-wave (32 lanes x 4 fp16 feats) per node, 8 nodes/block.
// Rows are pre-scaled by dinv[src]; inner loop is pure add. 16-deep MLP.
// ---------------------------------------------------------------------------
__device__ __forceinline__ void addv(float4& a, uint2 v) {
    __half2* h = (__half2*)&v;
    float2 f0 = __half22float2(h[0]);
    float2 f1 = __half22float2(h[1]);
    a.x += f0.x; a.y += f0.y; a.z += f1.x; a.w += f1.y;
}

// Layer 1: h1'[d] = dinv[d] * relu(dinv[d]*(sum + self) + b1), packed fp16.
__global__ __launch_bounds__(256) void aggregate_relu(
        const __half* __restrict__ hw, const int* __restrict__ rp,
        const int* __restrict__ em, const float* __restrict__ dinv,
        const float* __restrict__ bias, __half* __restrict__ out, int n) {
    const int lane = threadIdx.x & 31;
    const int node = blockIdx.x * 8 + (threadIdx.x >> 5);
    if (node >= n) return;
    const uint2* T = (const uint2*)hw;
    int e0 = rp[node], e1 = rp[node + 1];
    float4 a{0.f, 0.f, 0.f, 0.f};
    int e = e0;
    for (; e + 16 <= e1; e += 16) {
        uint2 v[16];
#pragma unroll
        for (int k = 0; k < 16; ++k) v[k] = T[(size_t)em[e + k] * 32 + lane];
#pragma unroll
        for (int k = 0; k < 16; ++k) addv(a, v[k]);
    }
    for (; e + 4 <= e1; e += 4) {
        uint2 v[4];
#pragma unroll
        for (int k = 0; k < 4; ++k) v[k] = T[(size_t)em[e + k] * 32 + lane];
#pragma unroll
        for (int k = 0; k < 4; ++k) addv(a, v[k]);
    }
    for (; e < e1; ++e) addv(a, T[(size_t)em[e] * 32 + lane]);
    addv(a, T[(size_t)node * 32 + lane]);          // self loop (pre-scaled row)
    float dv = dinv[node];
    float4 b = ((const float4*)bias)[lane];
    a.x = dv * fmaxf(fmaf(dv, a.x, b.x), 0.f);
    a.y = dv * fmaxf(fmaf(dv, a.y, b.y), 0.f);
    a.z = dv * fmaxf(fmaf(dv, a.z, b.z), 0.f);
    a.w = dv * fmaxf(fmaf(dv, a.w, b.w), 0.f);
    union { __half2 h[2]; uint2 u; } pk;
    pk.h[0] = __floats2half2_rn(a.x, a.y);
    pk.h[1] = __floats2half2_rn(a.z, a.w);
    ((uint2*)out)[(size_t)node * 32 + lane] = pk.u;
}

// Layer 2 pooled: pool[batch[d]] += dinv[d]*(sum + self). LDS-merge by graph
// (batch sorted), then atomics.
__global__ __launch_bounds__(256) void aggregate_pool(
        const __half* __restrict__ h1, const int* __restrict__ rp,
        const int* __restrict__ em, const float* __restrict__ dinv,
        const int* __restrict__ batch, float* __restrict__ pool, int n) {
    __shared__ float4 part[8][32];
    __shared__ int gs[8];
    const int lane = threadIdx.x & 31;
    const int half = threadIdx.x >> 5;
    const int node = blockIdx.x * 8 + half;
    const bool valid = node < n;
    const uint2* T = (const uint2*)h1;
    int e0 = 0, e1 = 0;
    if (valid) { e0 = rp[node]; e1 = rp[node + 1]; }
    float4 a{0.f, 0.f, 0.f, 0.f};
    int e = e0;
    for (; e + 16 <= e1; e += 16) {
        uint2 v[16];
#pragma unroll
        for (int k = 0; k < 16; ++k) v[k] = T[(size_t)em[e + k] * 32 + lane];
#pragma unroll
        for (int k = 0; k < 16; ++k) addv(a, v[k]);
    }
    for (; e + 4 <= e1; e += 4) {
        uint2 v[4];
#pragma unroll
        for (int k = 0; k < 4; ++k) v[k] = T[(size_t)em[e + k] * 32 + lane];
#pragma unroll
        for (int k = 0; k < 4; ++k) addv(a, v[k]);
    }
    for (; e < e1; ++e) addv(a, T[(size_t)em[e] * 32 + lane]);
    if (valid) {
        addv(a, T[(size_t)node * 32 + lane]);      // self loop
        float dv = dinv[node];
        a.x *= dv; a.y *= dv; a.z *= dv; a.w *= dv;
    }
    part[half][lane] = a;
    if (lane == 0) gs[half] = valid ? batch[node] : -1;
    __syncthreads();
    if (half == 0) {
        float4 acc = part[0][lane];
        int g0 = gs[0];
#pragma unroll
        for (int h = 1; h < 8; ++h) {
            if (gs[h] == g0) {
                float4 p = part[h][lane];
                acc.x += p.x; acc.y += p.y; acc.z += p.z; acc.w += p.w;
            } else {
                if (g0 >= 0) {
                    float* dstp = &pool[g0 * FDIM + lane * 4];
                    atomicAdd(dstp + 0, acc.x); atomicAdd(dstp + 1, acc.y);
                    atomicAdd(dstp + 2, acc.z); atomicAdd(dstp + 3, acc.w);
                }
                g0 = gs[h];
                acc = part[h][lane];
            }
        }
        if (g0 >= 0) {
            float* dstp = &pool[g0 * FDIM + lane * 4];
            atomicAdd(dstp + 0, acc.x); atomicAdd(dstp + 1, acc.y);
            atomicAdd(dstp + 2, acc.z); atomicAdd(dstp + 3, acc.w);
        }
    }
}

// out[g] = (pool[g]/cnt[g]) @ W2 + b2   (b2 suppressed for empty graphs)
__global__ __launch_bounds__(256) void pool_gemm(const float* __restrict__ pool,
                                                 const int* __restrict__ gcnt,
                                                 const float* __restrict__ W2,
                                                 const float* __restrict__ b2,
                                                 float* __restrict__ out, int G) {
    __shared__ float Ws[FDIM * FDIM];   // 64 KiB
    __shared__ float row[2][FDIM];
    for (int i = threadIdx.x; i < FDIM * FDIM; i += 256) Ws[i] = W2[i];
    const int j  = threadIdx.x & 127;
    const int gh = threadIdx.x >> 7;
    for (int g0 = blockIdx.x * 2; g0 < G; g0 += gridDim.x * 2) {
        const int g = g0 + gh;
        __syncthreads();
        int c = 0;
        if (g < G) {
            c = gcnt[g];
            float inv = (c > 0) ? 1.0f / (float)c : 0.0f;
            row[gh][j] = pool[g * FDIM + j] * inv;
        }
        __syncthreads();
        if (g < G) {
            float acc = (c > 0) ? b2[j] : 0.0f;
#pragma unroll
            for (int k = 0; k < FDIM; ++k)
                acc = fmaf(row[gh][k], Ws[k * FDIM + j], acc);
            out[g * FDIM + j] = acc;
        }
    }
}

// ---------------------------------------------------------------------------

extern "C" void kernel_launch(void* const* d_in, const int* in_sizes, int n_in,
                              void* d_out, int out_size, void* d_ws, size_t ws_size,
                              hipStream_t stream) {
    const float* x     = (const float*)d_in[0];
    const int*   ei    = (const int*)d_in[1];
    const int*   batch = (const int*)d_in[2];
    const float* W1    = (const float*)d_in[3];
    const float* b1    = (const float*)d_in[4];
    const float* W2    = (const float*)d_in[5];
    const float* b2    = (const float*)d_in[6];
    float* out = (float*)d_out;

    const int N = in_sizes[0] / FDIM;      // 100000
    const int E = in_sizes[1] / 2;         // 1600000
    const int G = out_size / FDIM;         // 1000
    const int* src = ei;
    const int* dst = ei + E;
    const int nbuck = (N + BNODES - 1) >> BSHIFT;   // 196

    char* p = (char*)d_ws;
    auto alloc = [&](size_t bytes) {
        void* r = (void*)p;
        p += (bytes + 255) & ~(size_t)255;
        return r;
    };
    float*    dinv  = (float*)   alloc((size_t)N * 4);
    int*      rp    = (int*)     alloc((size_t)(N + 1) * 4);
    int*      gcnt  = (int*)     alloc((size_t)G * 4);
    int*      bcnt  = (int*)     alloc(256 * 4);
    int*      bbase = (int*)     alloc(257 * 4);
    int*      bcur  = (int*)     alloc(256 * 4);
    unsigned* ebp   = (unsigned*)alloc((size_t)E * 4);
    int*      em    = (int*)     alloc((size_t)E * 4);
    __half*   hw    = (__half*)  alloc((size_t)N * FDIM * 2);
    __half*   h1    = (__half*)  alloc((size_t)N * FDIM * 2);
    float*    pool  = (float*)   alloc((size_t)G * FDIM * 4);

    hipMemsetAsync(bcnt, 0, 256 * 4, stream);
    hipMemsetAsync(gcnt, 0, (size_t)G * 4, stream);
    hipMemsetAsync(pool, 0, (size_t)G * FDIM * 4, stream);

    // CSR build
    bucket_count<<<1024, 256, 0, stream>>>(dst, bcnt, E);
    bucket_scan<<<1, 256, 0, stream>>>(bcnt, bbase, bcur, rp, E, N, nbuck);
    binscatter<<<(E + EPB - 1) / EPB, 256, 0, stream>>>(src, dst, bcur, ebp, E);
    csr_build<<<nbuck, 256, 0, stream>>>(ebp, bbase, batch, rp, dinv, em, gcnt, N);

    const int GB = (N + BROWS - 1) / BROWS;
    // layer 1: hw' = dinv*(x@W1) fp16; h1' = dinv*relu(dinv*agg + b1) fp16
    gemm128<<<GB, 256, 0, stream>>>(x, W1, dinv, hw, N);
    aggregate_relu<<<(N + 7) / 8, 256, 0, stream>>>(hw, rp, em, dinv, b1, h1, N);
    // layer 2: pool(A h1) -> [G,128], then micro-gemm with W2 + b2 + mean div
    aggregate_pool<<<(N + 7) / 8, 256, 0, stream>>>(h1, rp, em, dinv, batch, pool, N);
    pool_gemm<<<64, 256, 0, stream>>>(pool, gcnt, W2, b2, out, G);
}